// Round 1
// baseline (817.671 us; speedup 1.0000x reference)
//
#include <hip/hip_runtime.h>

// ---------------- wave helpers (wave = 64 lanes on CDNA) ----------------
static __device__ __forceinline__ float wred_max(float v) {
#pragma unroll
  for (int o = 32; o > 0; o >>= 1) v = fmaxf(v, __shfl_xor(v, o));
  return v;
}
static __device__ __forceinline__ float wred_sum(float v) {
#pragma unroll
  for (int o = 32; o > 0; o >>= 1) v += __shfl_xor(v, o);
  return v;
}
static __device__ __forceinline__ float lrelu(float x) { return x > 0.f ? x : 0.2f * x; }

// ---------------- preprocessing: CSR build ----------------
__global__ void zero_int2(int* __restrict__ a, int* __restrict__ b, int n) {
  int i = blockIdx.x * blockDim.x + threadIdx.x;
  if (i < n) { a[i] = 0; b[i] = 0; }
}

__global__ void count_deg(const int* __restrict__ dst, int* __restrict__ deg, int E) {
  int i = blockIdx.x * blockDim.x + threadIdx.x;
  if (i < E) atomicAdd(&deg[dst[i]], 1);
}

// single-block exclusive scan (N=50k -> 49 chunks of 1024, fast enough)
__global__ void scan_deg(const int* __restrict__ deg, int* __restrict__ row_start, int n) {
  __shared__ int sd[1024];
  __shared__ int s_off;
  int tid = threadIdx.x;
  if (tid == 0) s_off = 0;
  __syncthreads();
  for (int base = 0; base < n; base += 1024) {
    int i = base + tid;
    int v = (i < n) ? deg[i] : 0;
    sd[tid] = v;
    __syncthreads();
#pragma unroll
    for (int d = 1; d < 1024; d <<= 1) {
      int t = (tid >= d) ? sd[tid - d] : 0;
      __syncthreads();
      sd[tid] += t;
      __syncthreads();
    }
    int off = s_off;
    if (i < n) row_start[i] = off + sd[tid] - v;
    __syncthreads();
    if (tid == 0) s_off = off + sd[1023];
    __syncthreads();
  }
  if (tid == 0) row_start[n] = s_off;
}

__global__ void scatter_edges(const int* __restrict__ src, const int* __restrict__ dst,
                              const int* __restrict__ row_start, int* __restrict__ cursor,
                              int* __restrict__ src_sorted, int* __restrict__ eid_sorted, int E) {
  int i = blockIdx.x * blockDim.x + threadIdx.x;
  if (i < E) {
    int d = dst[i];
    int pos = row_start[d] + atomicAdd(&cursor[d], 1);
    src_sorted[pos] = src[i];
    eid_sorted[pos] = i;
  }
}

// ---------------- edge-coefficient vectors: wv[k][d], k=0..8 (L0 h0..3, L1 h0..3, L2 h0) ----------------
__global__ void wvec_kernel(const float* __restrict__ We0, const float* __restrict__ ae0w,
                            const float* __restrict__ We1, const float* __restrict__ ae1w,
                            const float* __restrict__ We2, const float* __restrict__ ae2w,
                            float* __restrict__ wv) {
  int t = threadIdx.x;
  if (t < 144) {
    int k = t >> 4, d = t & 15;
    const float* We; const float* aev; int h; int HC;
    if (k < 4)      { We = We0; aev = ae0w; h = k;     HC = 256; }
    else if (k < 8) { We = We1; aev = ae1w; h = k - 4; HC = 256; }
    else            { We = We2; aev = ae2w; h = 0;     HC = 64; }
    float sum = 0.f;
#pragma unroll
    for (int c = 0; c < 64; ++c) sum += We[(size_t)d * HC + h * 64 + c] * aev[h * 64 + c];
    wv[k * 16 + d] = sum;
  }
}

// per-edge attention coefficients for all 3 layers, stored in CSR-sorted order
__global__ __launch_bounds__(256) void edge_ae(const float* __restrict__ ea,
                                               const int* __restrict__ eid_sorted,
                                               const float* __restrict__ wv,
                                               float* __restrict__ ae0, float* __restrict__ ae1,
                                               float* __restrict__ ae2, int E) {
  __shared__ float swv[144];
  if (threadIdx.x < 144) swv[threadIdx.x] = wv[threadIdx.x];
  __syncthreads();
  int p = blockIdx.x * blockDim.x + threadIdx.x;
  if (p >= E) return;
  int e = eid_sorted[p];
  const float4* er = (const float4*)(ea + (size_t)e * 16);
  float4 v0 = er[0], v1 = er[1], v2 = er[2], v3 = er[3];
  float ev[16] = {v0.x, v0.y, v0.z, v0.w, v1.x, v1.y, v1.z, v1.w,
                  v2.x, v2.y, v2.z, v2.w, v3.x, v3.y, v3.z, v3.w};
  float r[9];
#pragma unroll
  for (int k = 0; k < 9; ++k) {
    float s = 0.f;
#pragma unroll
    for (int d = 0; d < 16; ++d) s += ev[d] * swv[k * 16 + d];
    r[k] = s;
  }
  *(float4*)(ae0 + (size_t)p * 4) = make_float4(r[0], r[1], r[2], r[3]);
  *(float4*)(ae1 + (size_t)p * 4) = make_float4(r[4], r[5], r[6], r[7]);
  ae2[p] = r[8];
}

// ---------------- f32 GEMM: C[M,Nc] = A[M,K] @ B[K,Nc], 128x128x16 tile, 8x8/thread ----------------
__global__ __launch_bounds__(256) void gemm_f32(const float* __restrict__ A,
                                                const float* __restrict__ B,
                                                float* __restrict__ C, int M, int K, int Nc) {
  __shared__ float As[16][132];
  __shared__ float Bs[16][132];
  const int tid = threadIdx.x;
  const int bm = blockIdx.x * 128;
  const int bn = blockIdx.y * 128;
  const int tr = (tid >> 4) << 3;
  const int tc = (tid & 15) << 3;
  const int ar = tid >> 2;
  const int ac = (tid & 3) << 2;
  const int brr = tid >> 5;
  const int bcc = (tid & 31) << 2;
  float acc[8][8] = {};
  for (int k0 = 0; k0 < K; k0 += 16) {
#pragma unroll
    for (int half = 0; half < 2; ++half) {
      int row = bm + ar + half * 64;
      float4 av = make_float4(0, 0, 0, 0);
      if (row < M) av = *(const float4*)(A + (size_t)row * K + k0 + ac);
      As[ac + 0][ar + half * 64] = av.x;
      As[ac + 1][ar + half * 64] = av.y;
      As[ac + 2][ar + half * 64] = av.z;
      As[ac + 3][ar + half * 64] = av.w;
    }
#pragma unroll
    for (int half = 0; half < 2; ++half) {
      int krow = k0 + brr + half * 8;
      float4 bv = make_float4(0, 0, 0, 0);
      if (bn + bcc < Nc) bv = *(const float4*)(B + (size_t)krow * Nc + bn + bcc);
      *(float4*)&Bs[brr + half * 8][bcc] = bv;
    }
    __syncthreads();
#pragma unroll
    for (int kk = 0; kk < 16; ++kk) {
      float a[8], b[8];
      *(float4*)&a[0] = *(const float4*)&As[kk][tr];
      *(float4*)&a[4] = *(const float4*)&As[kk][tr + 4];
      *(float4*)&b[0] = *(const float4*)&Bs[kk][tc];
      *(float4*)&b[4] = *(const float4*)&Bs[kk][tc + 4];
#pragma unroll
      for (int i = 0; i < 8; ++i)
#pragma unroll
        for (int j = 0; j < 8; ++j) acc[i][j] = fmaf(a[i], b[j], acc[i][j]);
    }
    __syncthreads();
  }
#pragma unroll
  for (int i = 0; i < 8; ++i) {
    int row = bm + tr + i;
    if (row < M) {
#pragma unroll
      for (int j0 = 0; j0 < 8; j0 += 4) {
        int col = bn + tc + j0;
        if (col < Nc) {
          float4 v = make_float4(acc[i][j0], acc[i][j0 + 1], acc[i][j0 + 2], acc[i][j0 + 3]);
          *(float4*)(C + (size_t)row * Nc + col) = v;
        }
      }
    }
  }
}

// ---------------- per-node a_src/a_dst dots ----------------
__global__ __launch_bounds__(256) void asad4(const float* __restrict__ xp,
                                             const float* __restrict__ as_w,
                                             const float* __restrict__ ad_w,
                                             float* __restrict__ asb, float* __restrict__ adb, int N) {
  int wave = threadIdx.x >> 6, lane = threadIdx.x & 63;
  int n = blockIdx.x * 4 + wave;
  if (n >= N) return;
  const float* xr = xp + (size_t)n * 256;
  float s[4], d[4];
#pragma unroll
  for (int h = 0; h < 4; ++h) {
    float v = xr[h * 64 + lane];
    s[h] = v * as_w[h * 64 + lane];
    d[h] = v * ad_w[h * 64 + lane];
  }
#pragma unroll
  for (int h = 0; h < 4; ++h) { s[h] = wred_sum(s[h]); d[h] = wred_sum(d[h]); }
  if (lane == 0) {
#pragma unroll
    for (int h = 0; h < 4; ++h) { asb[(size_t)n * 4 + h] = s[h]; adb[(size_t)n * 4 + h] = d[h]; }
  }
}

__global__ __launch_bounds__(256) void asad1(const float* __restrict__ xp,
                                             const float* __restrict__ as_w,
                                             const float* __restrict__ ad_w,
                                             float* __restrict__ asb, float* __restrict__ adb, int N) {
  int wave = threadIdx.x >> 6, lane = threadIdx.x & 63;
  int n = blockIdx.x * 4 + wave;
  if (n >= N) return;
  float v = xp[(size_t)n * 64 + lane];
  float s = wred_sum(v * as_w[lane]);
  float d = wred_sum(v * ad_w[lane]);
  if (lane == 0) { asb[n] = s; adb[n] = d; }
}

// ---------------- fused segment-softmax + aggregation, heads=4 C=64 ----------------
__global__ __launch_bounds__(256) void agg_heads4(
    const float* __restrict__ xp, const int* __restrict__ src_sorted,
    const int* __restrict__ row_start, const float* __restrict__ asb,
    const float* __restrict__ adb, const float* __restrict__ ae,
    const float* __restrict__ bias, float* __restrict__ out, int N) {
  int wave = threadIdx.x >> 6, lane = threadIdx.x & 63;
  int n = blockIdx.x * 4 + wave;
  if (n >= N) return;
  int beg = row_start[n], end = row_start[n + 1];
  int deg = end - beg;
  float4 adn = *(const float4*)(adb + (size_t)n * 4);
  float4 asn = *(const float4*)(asb + (size_t)n * 4);
  float m0 = -1e30f, m1 = -1e30f, m2 = -1e30f, m3 = -1e30f;
  float aes0 = 0, aes1 = 0, aes2 = 0, aes3 = 0;
  // pass A: per-head max + a_edge sums (for self-loop mean)
  for (int base = beg; base < end; base += 64) {
    int j = base + lane;
    if (j < end) {
      int s = src_sorted[j];
      float4 asv = *(const float4*)(asb + (size_t)s * 4);
      float4 aev = *(const float4*)(ae + (size_t)j * 4);
      aes0 += aev.x; aes1 += aev.y; aes2 += aev.z; aes3 += aev.w;
      m0 = fmaxf(m0, lrelu(asv.x + adn.x + aev.x));
      m1 = fmaxf(m1, lrelu(asv.y + adn.y + aev.y));
      m2 = fmaxf(m2, lrelu(asv.z + adn.z + aev.z));
      m3 = fmaxf(m3, lrelu(asv.w + adn.w + aev.w));
    }
  }
  m0 = wred_max(m0); m1 = wred_max(m1); m2 = wred_max(m2); m3 = wred_max(m3);
  aes0 = wred_sum(aes0); aes1 = wred_sum(aes1); aes2 = wred_sum(aes2); aes3 = wred_sum(aes3);
  float invd = 1.f / fmaxf((float)deg, 1.f);
  float al0 = lrelu(asn.x + adn.x + aes0 * invd);
  float al1 = lrelu(asn.y + adn.y + aes1 * invd);
  float al2 = lrelu(asn.z + adn.z + aes2 * invd);
  float al3 = lrelu(asn.w + adn.w + aes3 * invd);
  m0 = fmaxf(m0, al0); m1 = fmaxf(m1, al1); m2 = fmaxf(m2, al2); m3 = fmaxf(m3, al3);
  // pass B: exp weights + gather-accumulate
  float acc0 = 0, acc1 = 0, acc2 = 0, acc3 = 0;
  float den0 = 0, den1 = 0, den2 = 0, den3 = 0;
  for (int base = beg; base < end; base += 64) {
    int j = base + lane;
    float ex0 = 0, ex1 = 0, ex2 = 0, ex3 = 0;
    int s = 0;
    if (j < end) {
      s = src_sorted[j];
      float4 asv = *(const float4*)(asb + (size_t)s * 4);
      float4 aev = *(const float4*)(ae + (size_t)j * 4);
      ex0 = __expf(lrelu(asv.x + adn.x + aev.x) - m0);
      ex1 = __expf(lrelu(asv.y + adn.y + aev.y) - m1);
      ex2 = __expf(lrelu(asv.z + adn.z + aev.z) - m2);
      ex3 = __expf(lrelu(asv.w + adn.w + aev.w) - m3);
      den0 += ex0; den1 += ex1; den2 += ex2; den3 += ex3;
    }
    int cnt = min(64, end - base);
    for (int t = 0; t < cnt; ++t) {
      int sj = __shfl(s, t);
      float w0 = __shfl(ex0, t), w1 = __shfl(ex1, t), w2 = __shfl(ex2, t), w3 = __shfl(ex3, t);
      const float* xr = xp + (size_t)sj * 256;
      acc0 = fmaf(w0, xr[lane], acc0);
      acc1 = fmaf(w1, xr[64 + lane], acc1);
      acc2 = fmaf(w2, xr[128 + lane], acc2);
      acc3 = fmaf(w3, xr[192 + lane], acc3);
    }
  }
  den0 = wred_sum(den0); den1 = wred_sum(den1); den2 = wred_sum(den2); den3 = wred_sum(den3);
  float exl0 = __expf(al0 - m0), exl1 = __expf(al1 - m1), exl2 = __expf(al2 - m2), exl3 = __expf(al3 - m3);
  den0 += exl0; den1 += exl1; den2 += exl2; den3 += exl3;
  const float* xn = xp + (size_t)n * 256;
  acc0 = fmaf(exl0, xn[lane], acc0);
  acc1 = fmaf(exl1, xn[64 + lane], acc1);
  acc2 = fmaf(exl2, xn[128 + lane], acc2);
  acc3 = fmaf(exl3, xn[192 + lane], acc3);
  float* orow = out + (size_t)n * 256;
  orow[lane]       = fmaxf(acc0 / (den0 + 1e-16f) + bias[lane], 0.f);
  orow[64 + lane]  = fmaxf(acc1 / (den1 + 1e-16f) + bias[64 + lane], 0.f);
  orow[128 + lane] = fmaxf(acc2 / (den2 + 1e-16f) + bias[128 + lane], 0.f);
  orow[192 + lane] = fmaxf(acc3 / (den3 + 1e-16f) + bias[192 + lane], 0.f);
}

// ---------------- layer2 (heads=1) + final linear + sigmoid, fused ----------------
__global__ __launch_bounds__(256) void agg1_final(
    const float* __restrict__ xp, const int* __restrict__ src_sorted,
    const int* __restrict__ row_start, const float* __restrict__ asb,
    const float* __restrict__ adb, const float* __restrict__ ae,
    const float* __restrict__ b2, const float* __restrict__ lin_w,
    const float* __restrict__ lin_b, float* __restrict__ out, int N) {
  int wave = threadIdx.x >> 6, lane = threadIdx.x & 63;
  int n = blockIdx.x * 4 + wave;
  if (n >= N) return;
  int beg = row_start[n], end = row_start[n + 1];
  int deg = end - beg;
  float adn = adb[n], asn = asb[n];
  float m = -1e30f, aes = 0;
  for (int base = beg; base < end; base += 64) {
    int j = base + lane;
    if (j < end) {
      int s = src_sorted[j];
      float aev = ae[j];
      aes += aev;
      m = fmaxf(m, lrelu(asb[s] + adn + aev));
    }
  }
  m = wred_max(m);
  aes = wred_sum(aes);
  float al = lrelu(asn + adn + aes / fmaxf((float)deg, 1.f));
  m = fmaxf(m, al);
  float acc = 0, den = 0;
  for (int base = beg; base < end; base += 64) {
    int j = base + lane;
    float ex = 0;
    int s = 0;
    if (j < end) {
      s = src_sorted[j];
      ex = __expf(lrelu(asb[s] + adn + ae[j]) - m);
      den += ex;
    }
    int cnt = min(64, end - base);
    for (int t = 0; t < cnt; ++t) {
      int sj = __shfl(s, t);
      float w = __shfl(ex, t);
      acc = fmaf(w, xp[(size_t)sj * 64 + lane], acc);
    }
  }
  den = wred_sum(den);
  float exl = __expf(al - m);
  den += exl;
  acc = fmaf(exl, xp[(size_t)n * 64 + lane], acc);
  float h = fmaxf(acc / (den + 1e-16f) + b2[lane], 0.f);
  float p = wred_sum(h * lin_w[lane]);
  if (lane == 0) out[n] = 1.f / (1.f + __expf(-(p + lin_b[0])));
}

// ---------------- host glue ----------------
extern "C" void kernel_launch(void* const* d_in, const int* in_sizes, int n_in,
                              void* d_out, int out_size, void* d_ws, size_t ws_size,
                              hipStream_t stream) {
  const float* x    = (const float*)d_in[0];
  const int*   ei   = (const int*)d_in[1];
  const float* ea   = (const float*)d_in[2];
  const float* W0   = (const float*)d_in[3];
  const float* as0w = (const float*)d_in[4];
  const float* ad0w = (const float*)d_in[5];
  const float* We0  = (const float*)d_in[6];
  const float* ae0w = (const float*)d_in[7];
  const float* b0   = (const float*)d_in[8];
  const float* W1   = (const float*)d_in[9];
  const float* as1w = (const float*)d_in[10];
  const float* ad1w = (const float*)d_in[11];
  const float* We1  = (const float*)d_in[12];
  const float* ae1w = (const float*)d_in[13];
  const float* b1   = (const float*)d_in[14];
  const float* W2   = (const float*)d_in[15];
  const float* as2w = (const float*)d_in[16];
  const float* ad2w = (const float*)d_in[17];
  const float* We2  = (const float*)d_in[18];
  const float* ae2w = (const float*)d_in[19];
  const float* b2   = (const float*)d_in[20];
  const float* linw = (const float*)d_in[21];
  const float* linb = (const float*)d_in[22];

  const int N = in_sizes[0] / 128;
  const int E = in_sizes[1] / 2;
  const int* src = ei;
  const int* dst = ei + E;

  char* p = (char*)d_ws;
  auto alloc = [&](size_t bytes) {
    char* r = p;
    p += (bytes + 255) & ~size_t(255);
    return r;
  };
  float* bufA       = (float*)alloc((size_t)N * 256 * 4);
  float* bufB       = (float*)alloc((size_t)N * 256 * 4);
  float* asb        = (float*)alloc((size_t)N * 4 * 4);
  float* adb        = (float*)alloc((size_t)N * 4 * 4);
  int*   src_sorted = (int*)alloc((size_t)E * 4);
  int*   eid_sorted = (int*)alloc((size_t)E * 4);
  float* ae0s       = (float*)alloc((size_t)E * 4 * 4);
  float* ae1s       = (float*)alloc((size_t)E * 4 * 4);
  float* ae2s       = (float*)alloc((size_t)E * 4);
  int*   deg        = (int*)alloc((size_t)N * 4);
  int*   row_start  = (int*)alloc((size_t)(N + 1) * 4);
  int*   cursor     = (int*)alloc((size_t)N * 4);
  float* wv         = (float*)alloc(144 * 4);

  int nb = (N + 255) / 256;
  int eb = (E + 255) / 256;
  zero_int2<<<nb, 256, 0, stream>>>(deg, cursor, N);
  count_deg<<<eb, 256, 0, stream>>>(dst, deg, E);
  scan_deg<<<1, 1024, 0, stream>>>(deg, row_start, N);
  scatter_edges<<<eb, 256, 0, stream>>>(src, dst, row_start, cursor, src_sorted, eid_sorted, E);
  wvec_kernel<<<1, 160, 0, stream>>>(We0, ae0w, We1, ae1w, We2, ae2w, wv);
  edge_ae<<<eb, 256, 0, stream>>>(ea, eid_sorted, wv, ae0s, ae1s, ae2s, E);

  dim3 blk(256);
  int gm = (N + 127) / 128;
  int nwb = (N + 3) / 4;
  // layer 0
  gemm_f32<<<dim3(gm, 2), blk, 0, stream>>>(x, W0, bufB, N, 128, 256);
  asad4<<<nwb, 256, 0, stream>>>(bufB, as0w, ad0w, asb, adb, N);
  agg_heads4<<<nwb, 256, 0, stream>>>(bufB, src_sorted, row_start, asb, adb, ae0s, b0, bufA, N);
  // layer 1
  gemm_f32<<<dim3(gm, 2), blk, 0, stream>>>(bufA, W1, bufB, N, 256, 256);
  asad4<<<nwb, 256, 0, stream>>>(bufB, as1w, ad1w, asb, adb, N);
  agg_heads4<<<nwb, 256, 0, stream>>>(bufB, src_sorted, row_start, asb, adb, ae1s, b1, bufA, N);
  // layer 2 + final linear + sigmoid
  gemm_f32<<<dim3(gm, 1), blk, 0, stream>>>(bufA, W2, bufB, N, 256, 64);
  asad1<<<nwb, 256, 0, stream>>>(bufB, as2w, ad2w, asb, adb, N);
  agg1_final<<<nwb, 256, 0, stream>>>(bufB, src_sorted, row_start, asb, adb, ae2s, b2, linw, linb,
                                      (float*)d_out, N);
}

// Round 2
// 740.045 us; speedup vs baseline: 1.1049x; 1.1049x over previous
//
#include <hip/hip_runtime.h>
#include <hip/hip_fp16.h>

// ---------------- wave helpers (wave = 64 lanes on CDNA) ----------------
static __device__ __forceinline__ float wred_max(float v) {
#pragma unroll
  for (int o = 32; o > 0; o >>= 1) v = fmaxf(v, __shfl_xor(v, o));
  return v;
}
static __device__ __forceinline__ float wred_sum(float v) {
#pragma unroll
  for (int o = 32; o > 0; o >>= 1) v += __shfl_xor(v, o);
  return v;
}
static __device__ __forceinline__ float lrelu(float x) { return x > 0.f ? x : 0.2f * x; }

// ---------------- preprocessing: CSR build ----------------
__global__ void zero_int2(int* __restrict__ a, int* __restrict__ b, int n) {
  int i = blockIdx.x * blockDim.x + threadIdx.x;
  if (i < n) { a[i] = 0; b[i] = 0; }
}

__global__ void count_deg(const int* __restrict__ dst, int* __restrict__ deg, int E) {
  int i = blockIdx.x * blockDim.x + threadIdx.x;
  if (i < E) atomicAdd(&deg[dst[i]], 1);
}

// single-block exclusive scan (N=50k -> 49 chunks of 1024, fast enough)
__global__ void scan_deg(const int* __restrict__ deg, int* __restrict__ row_start, int n) {
  __shared__ int sd[1024];
  __shared__ int s_off;
  int tid = threadIdx.x;
  if (tid == 0) s_off = 0;
  __syncthreads();
  for (int base = 0; base < n; base += 1024) {
    int i = base + tid;
    int v = (i < n) ? deg[i] : 0;
    sd[tid] = v;
    __syncthreads();
#pragma unroll
    for (int d = 1; d < 1024; d <<= 1) {
      int t = (tid >= d) ? sd[tid - d] : 0;
      __syncthreads();
      sd[tid] += t;
      __syncthreads();
    }
    int off = s_off;
    if (i < n) row_start[i] = off + sd[tid] - v;
    __syncthreads();
    if (tid == 0) s_off = off + sd[1023];
    __syncthreads();
  }
  if (tid == 0) row_start[n] = s_off;
}

__global__ void scatter_edges(const int* __restrict__ src, const int* __restrict__ dst,
                              const int* __restrict__ row_start, int* __restrict__ cursor,
                              int* __restrict__ src_sorted, int* __restrict__ eid_sorted, int E) {
  int i = blockIdx.x * blockDim.x + threadIdx.x;
  if (i < E) {
    int d = dst[i];
    int pos = row_start[d] + atomicAdd(&cursor[d], 1);
    src_sorted[pos] = src[i];
    eid_sorted[pos] = i;
  }
}

// ---------------- edge-coefficient vectors: wv[k][d], k=0..8 (L0 h0..3, L1 h0..3, L2 h0) ----------------
__global__ void wvec_kernel(const float* __restrict__ We0, const float* __restrict__ ae0w,
                            const float* __restrict__ We1, const float* __restrict__ ae1w,
                            const float* __restrict__ We2, const float* __restrict__ ae2w,
                            float* __restrict__ wv) {
  int t = threadIdx.x;
  if (t < 144) {
    int k = t >> 4, d = t & 15;
    const float* We; const float* aev; int h; int HC;
    if (k < 4)      { We = We0; aev = ae0w; h = k;     HC = 256; }
    else if (k < 8) { We = We1; aev = ae1w; h = k - 4; HC = 256; }
    else            { We = We2; aev = ae2w; h = 0;     HC = 64; }
    float sum = 0.f;
#pragma unroll
    for (int c = 0; c < 64; ++c) sum += We[(size_t)d * HC + h * 64 + c] * aev[h * 64 + c];
    wv[k * 16 + d] = sum;
  }
}

// per-edge attention coefficients for all 3 layers, stored in CSR-sorted order
__global__ __launch_bounds__(256) void edge_ae(const float* __restrict__ ea,
                                               const int* __restrict__ eid_sorted,
                                               const float* __restrict__ wv,
                                               float* __restrict__ ae0, float* __restrict__ ae1,
                                               float* __restrict__ ae2, int E) {
  __shared__ float swv[144];
  if (threadIdx.x < 144) swv[threadIdx.x] = wv[threadIdx.x];
  __syncthreads();
  int p = blockIdx.x * blockDim.x + threadIdx.x;
  if (p >= E) return;
  int e = eid_sorted[p];
  const float4* er = (const float4*)(ea + (size_t)e * 16);
  float4 v0 = er[0], v1 = er[1], v2 = er[2], v3 = er[3];
  float ev[16] = {v0.x, v0.y, v0.z, v0.w, v1.x, v1.y, v1.z, v1.w,
                  v2.x, v2.y, v2.z, v2.w, v3.x, v3.y, v3.z, v3.w};
  float r[9];
#pragma unroll
  for (int k = 0; k < 9; ++k) {
    float s = 0.f;
#pragma unroll
    for (int d = 0; d < 16; ++d) s += ev[d] * swv[k * 16 + d];
    r[k] = s;
  }
  *(float4*)(ae0 + (size_t)p * 4) = make_float4(r[0], r[1], r[2], r[3]);
  *(float4*)(ae1 + (size_t)p * 4) = make_float4(r[4], r[5], r[6], r[7]);
  ae2[p] = r[8];
}

// ---------------- f32 GEMM, fp16 output: C[M,Nc] = A[M,K] @ B[K,Nc] ----------------
__global__ __launch_bounds__(256) void gemm_f32h(const float* __restrict__ A,
                                                 const float* __restrict__ B,
                                                 __half* __restrict__ C, int M, int K, int Nc) {
  __shared__ float As[16][132];
  __shared__ float Bs[16][132];
  const int tid = threadIdx.x;
  const int bm = blockIdx.x * 128;
  const int bn = blockIdx.y * 128;
  const int tr = (tid >> 4) << 3;
  const int tc = (tid & 15) << 3;
  const int ar = tid >> 2;
  const int ac = (tid & 3) << 2;
  const int brr = tid >> 5;
  const int bcc = (tid & 31) << 2;
  float acc[8][8] = {};
  for (int k0 = 0; k0 < K; k0 += 16) {
#pragma unroll
    for (int half_ = 0; half_ < 2; ++half_) {
      int row = bm + ar + half_ * 64;
      float4 av = make_float4(0, 0, 0, 0);
      if (row < M) av = *(const float4*)(A + (size_t)row * K + k0 + ac);
      As[ac + 0][ar + half_ * 64] = av.x;
      As[ac + 1][ar + half_ * 64] = av.y;
      As[ac + 2][ar + half_ * 64] = av.z;
      As[ac + 3][ar + half_ * 64] = av.w;
    }
#pragma unroll
    for (int half_ = 0; half_ < 2; ++half_) {
      int krow = k0 + brr + half_ * 8;
      float4 bv = make_float4(0, 0, 0, 0);
      if (bn + bcc < Nc) bv = *(const float4*)(B + (size_t)krow * Nc + bn + bcc);
      *(float4*)&Bs[brr + half_ * 8][bcc] = bv;
    }
    __syncthreads();
#pragma unroll
    for (int kk = 0; kk < 16; ++kk) {
      float a[8], b[8];
      *(float4*)&a[0] = *(const float4*)&As[kk][tr];
      *(float4*)&a[4] = *(const float4*)&As[kk][tr + 4];
      *(float4*)&b[0] = *(const float4*)&Bs[kk][tc];
      *(float4*)&b[4] = *(const float4*)&Bs[kk][tc + 4];
#pragma unroll
      for (int i = 0; i < 8; ++i)
#pragma unroll
        for (int j = 0; j < 8; ++j) acc[i][j] = fmaf(a[i], b[j], acc[i][j]);
    }
    __syncthreads();
  }
#pragma unroll
  for (int i = 0; i < 8; ++i) {
    int row = bm + tr + i;
    if (row < M) {
#pragma unroll
      for (int j0 = 0; j0 < 8; j0 += 4) {
        int col = bn + tc + j0;
        if (col < Nc) {
          __half2 p0 = __floats2half2_rn(acc[i][j0], acc[i][j0 + 1]);
          __half2 p1 = __floats2half2_rn(acc[i][j0 + 2], acc[i][j0 + 3]);
          uint2 u;
          u.x = *(unsigned int*)&p0;
          u.y = *(unsigned int*)&p1;
          *(uint2*)(C + (size_t)row * Nc + col) = u;
        }
      }
    }
  }
}

// ---------------- per-node a_src/a_dst dots (fp16 xp) ----------------
__global__ __launch_bounds__(256) void asad4(const __half* __restrict__ xp,
                                             const float* __restrict__ as_w,
                                             const float* __restrict__ ad_w,
                                             float* __restrict__ asb, float* __restrict__ adb, int N) {
  int wave = threadIdx.x >> 6, lane = threadIdx.x & 63;
  int n = blockIdx.x * 4 + wave;
  if (n >= N) return;
  const __half* xr = xp + (size_t)n * 256;
  float s[4], d[4];
#pragma unroll
  for (int h = 0; h < 4; ++h) {
    float v = __half2float(xr[h * 64 + lane]);
    s[h] = v * as_w[h * 64 + lane];
    d[h] = v * ad_w[h * 64 + lane];
  }
#pragma unroll
  for (int h = 0; h < 4; ++h) { s[h] = wred_sum(s[h]); d[h] = wred_sum(d[h]); }
  if (lane == 0) {
#pragma unroll
    for (int h = 0; h < 4; ++h) { asb[(size_t)n * 4 + h] = s[h]; adb[(size_t)n * 4 + h] = d[h]; }
  }
}

__global__ __launch_bounds__(256) void asad1(const __half* __restrict__ xp,
                                             const float* __restrict__ as_w,
                                             const float* __restrict__ ad_w,
                                             float* __restrict__ asb, float* __restrict__ adb, int N) {
  int wave = threadIdx.x >> 6, lane = threadIdx.x & 63;
  int n = blockIdx.x * 4 + wave;
  if (n >= N) return;
  float v = __half2float(xp[(size_t)n * 64 + lane]);
  float s = wred_sum(v * as_w[lane]);
  float d = wred_sum(v * ad_w[lane]);
  if (lane == 0) { asb[n] = s; adb[n] = d; }
}

// ---------------- fused segment-softmax + aggregation, heads=4 C=64, fp16 gather ----------------
// lane owns channels [4*lane, 4*lane+4); head of lane = lane>>4
__global__ __launch_bounds__(256) void agg_heads4(
    const __half* __restrict__ xp, const int* __restrict__ src_sorted,
    const int* __restrict__ row_start, const float* __restrict__ asb,
    const float* __restrict__ adb, const float* __restrict__ ae,
    const float* __restrict__ bias, float* __restrict__ out, int N) {
  int wave = threadIdx.x >> 6, lane = threadIdx.x & 63;
  int n = blockIdx.x * 4 + wave;
  if (n >= N) return;
  int beg = row_start[n], end = row_start[n + 1];
  int deg = end - beg;
  int hsel = lane >> 4;
  float4 adn = *(const float4*)(adb + (size_t)n * 4);
  float4 asn = *(const float4*)(asb + (size_t)n * 4);
  float m0 = -1e30f, m1 = -1e30f, m2 = -1e30f, m3 = -1e30f;
  float aes0 = 0, aes1 = 0, aes2 = 0, aes3 = 0;
  // pass A: per-head max + a_edge sums (for self-loop mean)
  for (int base = beg; base < end; base += 64) {
    int j = base + lane;
    if (j < end) {
      int s = src_sorted[j];
      float4 asv = *(const float4*)(asb + (size_t)s * 4);
      float4 aev = *(const float4*)(ae + (size_t)j * 4);
      aes0 += aev.x; aes1 += aev.y; aes2 += aev.z; aes3 += aev.w;
      m0 = fmaxf(m0, lrelu(asv.x + adn.x + aev.x));
      m1 = fmaxf(m1, lrelu(asv.y + adn.y + aev.y));
      m2 = fmaxf(m2, lrelu(asv.z + adn.z + aev.z));
      m3 = fmaxf(m3, lrelu(asv.w + adn.w + aev.w));
    }
  }
  m0 = wred_max(m0); m1 = wred_max(m1); m2 = wred_max(m2); m3 = wred_max(m3);
  aes0 = wred_sum(aes0); aes1 = wred_sum(aes1); aes2 = wred_sum(aes2); aes3 = wred_sum(aes3);
  float invd = 1.f / fmaxf((float)deg, 1.f);
  float al0 = lrelu(asn.x + adn.x + aes0 * invd);
  float al1 = lrelu(asn.y + adn.y + aes1 * invd);
  float al2 = lrelu(asn.z + adn.z + aes2 * invd);
  float al3 = lrelu(asn.w + adn.w + aes3 * invd);
  m0 = fmaxf(m0, al0); m1 = fmaxf(m1, al1); m2 = fmaxf(m2, al2); m3 = fmaxf(m3, al3);
  // pass B: exp weights + gather-accumulate (4 consecutive fp16 channels / lane)
  float acc0 = 0, acc1 = 0, acc2 = 0, acc3 = 0;
  float den0 = 0, den1 = 0, den2 = 0, den3 = 0;
  for (int base = beg; base < end; base += 64) {
    int j = base + lane;
    float ex0 = 0, ex1 = 0, ex2 = 0, ex3 = 0;
    int s = 0;
    if (j < end) {
      s = src_sorted[j];
      float4 asv = *(const float4*)(asb + (size_t)s * 4);
      float4 aev = *(const float4*)(ae + (size_t)j * 4);
      ex0 = __expf(lrelu(asv.x + adn.x + aev.x) - m0);
      ex1 = __expf(lrelu(asv.y + adn.y + aev.y) - m1);
      ex2 = __expf(lrelu(asv.z + adn.z + aev.z) - m2);
      ex3 = __expf(lrelu(asv.w + adn.w + aev.w) - m3);
      den0 += ex0; den1 += ex1; den2 += ex2; den3 += ex3;
    }
    int cnt = min(64, end - base);
    for (int t = 0; t < cnt; ++t) {
      int sj = __shfl(s, t);
      float w0 = __shfl(ex0, t), w1 = __shfl(ex1, t), w2 = __shfl(ex2, t), w3 = __shfl(ex3, t);
      float w = hsel == 0 ? w0 : (hsel == 1 ? w1 : (hsel == 2 ? w2 : w3));
      uint2 u = *(const uint2*)(xp + (size_t)sj * 256 + (lane << 2));
      __half2 hA = *(__half2*)&u.x;
      __half2 hB = *(__half2*)&u.y;
      float2 fA = __half22float2(hA);
      float2 fB = __half22float2(hB);
      acc0 = fmaf(w, fA.x, acc0);
      acc1 = fmaf(w, fA.y, acc1);
      acc2 = fmaf(w, fB.x, acc2);
      acc3 = fmaf(w, fB.y, acc3);
    }
  }
  den0 = wred_sum(den0); den1 = wred_sum(den1); den2 = wred_sum(den2); den3 = wred_sum(den3);
  float exl0 = __expf(al0 - m0), exl1 = __expf(al1 - m1), exl2 = __expf(al2 - m2), exl3 = __expf(al3 - m3);
  den0 += exl0; den1 += exl1; den2 += exl2; den3 += exl3;
  float exh = hsel == 0 ? exl0 : (hsel == 1 ? exl1 : (hsel == 2 ? exl2 : exl3));
  {
    uint2 u = *(const uint2*)(xp + (size_t)n * 256 + (lane << 2));
    __half2 hA = *(__half2*)&u.x;
    __half2 hB = *(__half2*)&u.y;
    float2 fA = __half22float2(hA);
    float2 fB = __half22float2(hB);
    acc0 = fmaf(exh, fA.x, acc0);
    acc1 = fmaf(exh, fA.y, acc1);
    acc2 = fmaf(exh, fB.x, acc2);
    acc3 = fmaf(exh, fB.y, acc3);
  }
  float denh = hsel == 0 ? den0 : (hsel == 1 ? den1 : (hsel == 2 ? den2 : den3));
  float rden = 1.f / (denh + 1e-16f);
  float4 bv = *(const float4*)(bias + (lane << 2));
  float4 ov = make_float4(fmaxf(acc0 * rden + bv.x, 0.f), fmaxf(acc1 * rden + bv.y, 0.f),
                          fmaxf(acc2 * rden + bv.z, 0.f), fmaxf(acc3 * rden + bv.w, 0.f));
  *(float4*)(out + (size_t)n * 256 + (lane << 2)) = ov;
}

// ---------------- layer2 (heads=1) + final linear + sigmoid, fused, fp16 gather ----------------
__global__ __launch_bounds__(256) void agg1_final(
    const __half* __restrict__ xp, const int* __restrict__ src_sorted,
    const int* __restrict__ row_start, const float* __restrict__ asb,
    const float* __restrict__ adb, const float* __restrict__ ae,
    const float* __restrict__ b2, const float* __restrict__ lin_w,
    const float* __restrict__ lin_b, float* __restrict__ out, int N) {
  int wave = threadIdx.x >> 6, lane = threadIdx.x & 63;
  int n = blockIdx.x * 4 + wave;
  if (n >= N) return;
  int beg = row_start[n], end = row_start[n + 1];
  int deg = end - beg;
  float adn = adb[n], asn = asb[n];
  float m = -1e30f, aes = 0;
  for (int base = beg; base < end; base += 64) {
    int j = base + lane;
    if (j < end) {
      int s = src_sorted[j];
      float aev = ae[j];
      aes += aev;
      m = fmaxf(m, lrelu(asb[s] + adn + aev));
    }
  }
  m = wred_max(m);
  aes = wred_sum(aes);
  float al = lrelu(asn + adn + aes / fmaxf((float)deg, 1.f));
  m = fmaxf(m, al);
  float acc = 0, den = 0;
  for (int base = beg; base < end; base += 64) {
    int j = base + lane;
    float ex = 0;
    int s = 0;
    if (j < end) {
      s = src_sorted[j];
      ex = __expf(lrelu(asb[s] + adn + ae[j]) - m);
      den += ex;
    }
    int cnt = min(64, end - base);
    for (int t = 0; t < cnt; ++t) {
      int sj = __shfl(s, t);
      float w = __shfl(ex, t);
      acc = fmaf(w, __half2float(xp[(size_t)sj * 64 + lane]), acc);
    }
  }
  den = wred_sum(den);
  float exl = __expf(al - m);
  den += exl;
  acc = fmaf(exl, __half2float(xp[(size_t)n * 64 + lane]), acc);
  float h = fmaxf(acc / (den + 1e-16f) + b2[lane], 0.f);
  float p = wred_sum(h * lin_w[lane]);
  if (lane == 0) out[n] = 1.f / (1.f + __expf(-(p + lin_b[0])));
}

// ---------------- host glue ----------------
extern "C" void kernel_launch(void* const* d_in, const int* in_sizes, int n_in,
                              void* d_out, int out_size, void* d_ws, size_t ws_size,
                              hipStream_t stream) {
  const float* x    = (const float*)d_in[0];
  const int*   ei   = (const int*)d_in[1];
  const float* ea   = (const float*)d_in[2];
  const float* W0   = (const float*)d_in[3];
  const float* as0w = (const float*)d_in[4];
  const float* ad0w = (const float*)d_in[5];
  const float* We0  = (const float*)d_in[6];
  const float* ae0w = (const float*)d_in[7];
  const float* b0   = (const float*)d_in[8];
  const float* W1   = (const float*)d_in[9];
  const float* as1w = (const float*)d_in[10];
  const float* ad1w = (const float*)d_in[11];
  const float* We1  = (const float*)d_in[12];
  const float* ae1w = (const float*)d_in[13];
  const float* b1   = (const float*)d_in[14];
  const float* W2   = (const float*)d_in[15];
  const float* as2w = (const float*)d_in[16];
  const float* ad2w = (const float*)d_in[17];
  const float* We2  = (const float*)d_in[18];
  const float* ae2w = (const float*)d_in[19];
  const float* b2   = (const float*)d_in[20];
  const float* linw = (const float*)d_in[21];
  const float* linb = (const float*)d_in[22];

  const int N = in_sizes[0] / 128;
  const int E = in_sizes[1] / 2;
  const int* src = ei;
  const int* dst = ei + E;

  char* p = (char*)d_ws;
  auto alloc = [&](size_t bytes) {
    char* r = p;
    p += (bytes + 255) & ~size_t(255);
    return r;
  };
  float*  bufA       = (float*)alloc((size_t)N * 256 * 4);   // agg output (f32)
  __half* xph        = (__half*)alloc((size_t)N * 256 * 2);  // GEMM output (fp16 gather table)
  float*  asb        = (float*)alloc((size_t)N * 4 * 4);
  float*  adb        = (float*)alloc((size_t)N * 4 * 4);
  int*    src_sorted = (int*)alloc((size_t)E * 4);
  int*    eid_sorted = (int*)alloc((size_t)E * 4);
  float*  ae0s       = (float*)alloc((size_t)E * 4 * 4);
  float*  ae1s       = (float*)alloc((size_t)E * 4 * 4);
  float*  ae2s       = (float*)alloc((size_t)E * 4);
  int*    deg        = (int*)alloc((size_t)N * 4);
  int*    row_start  = (int*)alloc((size_t)(N + 1) * 4);
  int*    cursor     = (int*)alloc((size_t)N * 4);
  float*  wv         = (float*)alloc(144 * 4);

  int nb = (N + 255) / 256;
  int eb = (E + 255) / 256;
  zero_int2<<<nb, 256, 0, stream>>>(deg, cursor, N);
  count_deg<<<eb, 256, 0, stream>>>(dst, deg, E);
  scan_deg<<<1, 1024, 0, stream>>>(deg, row_start, N);
  scatter_edges<<<eb, 256, 0, stream>>>(src, dst, row_start, cursor, src_sorted, eid_sorted, E);
  wvec_kernel<<<1, 160, 0, stream>>>(We0, ae0w, We1, ae1w, We2, ae2w, wv);
  edge_ae<<<eb, 256, 0, stream>>>(ea, eid_sorted, wv, ae0s, ae1s, ae2s, E);

  dim3 blk(256);
  int gm = (N + 127) / 128;
  int nwb = (N + 3) / 4;
  // layer 0
  gemm_f32h<<<dim3(gm, 2), blk, 0, stream>>>(x, W0, xph, N, 128, 256);
  asad4<<<nwb, 256, 0, stream>>>(xph, as0w, ad0w, asb, adb, N);
  agg_heads4<<<nwb, 256, 0, stream>>>(xph, src_sorted, row_start, asb, adb, ae0s, b0, bufA, N);
  // layer 1
  gemm_f32h<<<dim3(gm, 2), blk, 0, stream>>>(bufA, W1, xph, N, 256, 256);
  asad4<<<nwb, 256, 0, stream>>>(xph, as1w, ad1w, asb, adb, N);
  agg_heads4<<<nwb, 256, 0, stream>>>(xph, src_sorted, row_start, asb, adb, ae1s, b1, bufA, N);
  // layer 2 + final linear + sigmoid
  gemm_f32h<<<dim3(gm, 1), blk, 0, stream>>>(bufA, W2, xph, N, 256, 64);
  asad1<<<nwb, 256, 0, stream>>>(xph, as2w, ad2w, asb, adb, N);
  agg1_final<<<nwb, 256, 0, stream>>>(xph, src_sorted, row_start, asb, adb, ae2s, b2, linw, linb,
                                      (float*)d_out, N);
}

// Round 3
// 588.157 us; speedup vs baseline: 1.3902x; 1.2582x over previous
//
#include <hip/hip_runtime.h>
#include <hip/hip_fp16.h>

using f16x8 = __attribute__((ext_vector_type(8))) _Float16;
using f32x4 = __attribute__((ext_vector_type(4))) float;

// ---------------- wave helpers (wave = 64 lanes on CDNA) ----------------
static __device__ __forceinline__ float wred_max(float v) {
#pragma unroll
  for (int o = 32; o > 0; o >>= 1) v = fmaxf(v, __shfl_xor(v, o));
  return v;
}
static __device__ __forceinline__ float wred_sum(float v) {
#pragma unroll
  for (int o = 32; o > 0; o >>= 1) v += __shfl_xor(v, o);
  return v;
}
static __device__ __forceinline__ float lrelu(float x) { return x > 0.f ? x : 0.2f * x; }

// ---------------- preprocessing: CSR build ----------------
__global__ void zero_int2(int* __restrict__ a, int* __restrict__ b, int n) {
  int i = blockIdx.x * blockDim.x + threadIdx.x;
  if (i < n) { a[i] = 0; b[i] = 0; }
}

__global__ void count_deg(const int* __restrict__ dst, int* __restrict__ deg, int E) {
  int i = blockIdx.x * blockDim.x + threadIdx.x;
  if (i < E) atomicAdd(&deg[dst[i]], 1);
}

__global__ void scan_deg(const int* __restrict__ deg, int* __restrict__ row_start, int n) {
  __shared__ int sd[1024];
  __shared__ int s_off;
  int tid = threadIdx.x;
  if (tid == 0) s_off = 0;
  __syncthreads();
  for (int base = 0; base < n; base += 1024) {
    int i = base + tid;
    int v = (i < n) ? deg[i] : 0;
    sd[tid] = v;
    __syncthreads();
#pragma unroll
    for (int d = 1; d < 1024; d <<= 1) {
      int t = (tid >= d) ? sd[tid - d] : 0;
      __syncthreads();
      sd[tid] += t;
      __syncthreads();
    }
    int off = s_off;
    if (i < n) row_start[i] = off + sd[tid] - v;
    __syncthreads();
    if (tid == 0) s_off = off + sd[1023];
    __syncthreads();
  }
  if (tid == 0) row_start[n] = s_off;
}

__global__ void scatter_edges(const int* __restrict__ src, const int* __restrict__ dst,
                              const int* __restrict__ row_start, int* __restrict__ cursor,
                              int* __restrict__ src_sorted, int* __restrict__ eid_sorted, int E) {
  int i = blockIdx.x * blockDim.x + threadIdx.x;
  if (i < E) {
    int d = dst[i];
    int pos = row_start[d] + atomicAdd(&cursor[d], 1);
    src_sorted[pos] = src[i];
    eid_sorted[pos] = i;
  }
}

// ---------------- weight prep: f32 -> f16, transposed ----------------
__global__ void transpose_w_f16(const float* __restrict__ W, __half* __restrict__ Wt, int K, int Nc) {
  int n = blockIdx.x * 16 + (threadIdx.x & 15);
  int k = blockIdx.y * 16 + (threadIdx.x >> 4);
  if (n < Nc && k < K) Wt[(size_t)n * K + k] = __float2half(W[(size_t)k * Nc + n]);
}

__global__ void convert_f32_f16(const float* __restrict__ in, __half* __restrict__ out, int n4) {
  int i = blockIdx.x * blockDim.x + threadIdx.x;
  if (i < n4) {
    float4 v = *(const float4*)(in + (size_t)i * 4);
    __half2 h01 = __floats2half2_rn(v.x, v.y);
    __half2 h23 = __floats2half2_rn(v.z, v.w);
    uint2 u;
    u.x = *(unsigned*)&h01;
    u.y = *(unsigned*)&h23;
    *(uint2*)(out + (size_t)i * 4) = u;
  }
}

// ---------------- edge-coefficient vectors: wv[k][d], k=0..8 ----------------
__global__ void wvec_kernel(const float* __restrict__ We0, const float* __restrict__ ae0w,
                            const float* __restrict__ We1, const float* __restrict__ ae1w,
                            const float* __restrict__ We2, const float* __restrict__ ae2w,
                            float* __restrict__ wv) {
  int t = threadIdx.x;
  if (t < 144) {
    int k = t >> 4, d = t & 15;
    const float* We; const float* aev; int h; int HC;
    if (k < 4)      { We = We0; aev = ae0w; h = k;     HC = 256; }
    else if (k < 8) { We = We1; aev = ae1w; h = k - 4; HC = 256; }
    else            { We = We2; aev = ae2w; h = 0;     HC = 64; }
    float sum = 0.f;
#pragma unroll
    for (int c = 0; c < 64; ++c) sum += We[(size_t)d * HC + h * 64 + c] * aev[h * 64 + c];
    wv[k * 16 + d] = sum;
  }
}

__global__ __launch_bounds__(256) void edge_ae(const float* __restrict__ ea,
                                               const int* __restrict__ eid_sorted,
                                               const float* __restrict__ wv,
                                               float* __restrict__ ae0, float* __restrict__ ae1,
                                               float* __restrict__ ae2, int E) {
  __shared__ float swv[144];
  if (threadIdx.x < 144) swv[threadIdx.x] = wv[threadIdx.x];
  __syncthreads();
  int p = blockIdx.x * blockDim.x + threadIdx.x;
  if (p >= E) return;
  int e = eid_sorted[p];
  const float4* er = (const float4*)(ea + (size_t)e * 16);
  float4 v0 = er[0], v1 = er[1], v2 = er[2], v3 = er[3];
  float ev[16] = {v0.x, v0.y, v0.z, v0.w, v1.x, v1.y, v1.z, v1.w,
                  v2.x, v2.y, v2.z, v2.w, v3.x, v3.y, v3.z, v3.w};
  float r[9];
#pragma unroll
  for (int k = 0; k < 9; ++k) {
    float s = 0.f;
#pragma unroll
    for (int d = 0; d < 16; ++d) s += ev[d] * swv[k * 16 + d];
    r[k] = s;
  }
  *(float4*)(ae0 + (size_t)p * 4) = make_float4(r[0], r[1], r[2], r[3]);
  *(float4*)(ae1 + (size_t)p * 4) = make_float4(r[4], r[5], r[6], r[7]);
  ae2[p] = r[8];
}

// ---------------- f16 MFMA GEMM: C[M,Nc] = A[M,K] @ Bt[Nc,K]^T ----------------
// BM=128, BK=64, 4 waves in 2x2; wave tile 64 x (BN/2); fragments 16x16x32.
template <int BN>
__global__ __launch_bounds__(256) void gemm_f16mfma(const __half* __restrict__ A,
                                                    const __half* __restrict__ Bt,
                                                    __half* __restrict__ C, int M, int K, int Nc) {
  constexpr int BM = 128, BK = 64;
  constexpr int LDT = BK + 8;  // f16 elems; row stride 144B -> bank advance 4 (free 2-way)
  constexpr int WN = BN / 2;
  constexpr int NFN = WN / 16;
  __shared__ __half As[BM][LDT];
  __shared__ __half Bs[BN][LDT];
  const int tid = threadIdx.x;
  const int lane = tid & 63, wave = tid >> 6;
  const int wr = wave >> 1, wc = wave & 1;
  const int bm = blockIdx.x * BM;
  const int bn = blockIdx.y * BN;
  const int r15 = lane & 15, kgrp = lane >> 4;
  f32x4 acc[4][NFN] = {};
  for (int k0 = 0; k0 < K; k0 += BK) {
    // stage A: 128 rows x 8 chunks(16B) = 1024 chunks / 256 threads
#pragma unroll
    for (int i = 0; i < 4; ++i) {
      int chunk = tid + i * 256;
      int row = chunk >> 3, kc = (chunk & 7) * 8;
      int grow = bm + row;
      float4 v = make_float4(0, 0, 0, 0);
      if (grow < M) v = *(const float4*)(A + (size_t)grow * K + k0 + kc);
      *(float4*)&As[row][kc] = v;
    }
    // stage B: BN rows x 8 chunks
#pragma unroll
    for (int i = 0; i < BN / 32; ++i) {
      int chunk = tid + i * 256;
      int row = chunk >> 3, kc = (chunk & 7) * 8;
      *(float4*)&Bs[row][kc] = *(const float4*)(Bt + (size_t)(bn + row) * K + k0 + kc);
    }
    __syncthreads();
#pragma unroll
    for (int kk = 0; kk < BK; kk += 32) {
      f16x8 af[4], bf[NFN];
#pragma unroll
      for (int mi = 0; mi < 4; ++mi)
        af[mi] = *(const f16x8*)&As[wr * 64 + mi * 16 + r15][kk + kgrp * 8];
#pragma unroll
      for (int ni = 0; ni < NFN; ++ni)
        bf[ni] = *(const f16x8*)&Bs[wc * WN + ni * 16 + r15][kk + kgrp * 8];
#pragma unroll
      for (int mi = 0; mi < 4; ++mi)
#pragma unroll
        for (int ni = 0; ni < NFN; ++ni)
          acc[mi][ni] = __builtin_amdgcn_mfma_f32_16x16x32_f16(af[mi], bf[ni], acc[mi][ni], 0, 0, 0);
    }
    __syncthreads();
  }
  // store: row = bm + wr*64 + mi*16 + kgrp*4 + r ; col = bn + wc*WN + ni*16 + r15
#pragma unroll
  for (int mi = 0; mi < 4; ++mi) {
#pragma unroll
    for (int r = 0; r < 4; ++r) {
      int grow = bm + wr * 64 + mi * 16 + kgrp * 4 + r;
      if (grow < M) {
#pragma unroll
        for (int ni = 0; ni < NFN; ++ni) {
          int gcol = bn + wc * WN + ni * 16 + r15;
          C[(size_t)grow * Nc + gcol] = __float2half(acc[mi][ni][r]);
        }
      }
    }
  }
}

// ---------------- per-node a_src/a_dst dots (fp16 xp) ----------------
__global__ __launch_bounds__(256) void asad4(const __half* __restrict__ xp,
                                             const float* __restrict__ as_w,
                                             const float* __restrict__ ad_w,
                                             float* __restrict__ asb, float* __restrict__ adb, int N) {
  int wave = threadIdx.x >> 6, lane = threadIdx.x & 63;
  int n = blockIdx.x * 4 + wave;
  if (n >= N) return;
  const __half* xr = xp + (size_t)n * 256;
  float s[4], d[4];
#pragma unroll
  for (int h = 0; h < 4; ++h) {
    float v = __half2float(xr[h * 64 + lane]);
    s[h] = v * as_w[h * 64 + lane];
    d[h] = v * ad_w[h * 64 + lane];
  }
#pragma unroll
  for (int h = 0; h < 4; ++h) { s[h] = wred_sum(s[h]); d[h] = wred_sum(d[h]); }
  if (lane == 0) {
#pragma unroll
    for (int h = 0; h < 4; ++h) { asb[(size_t)n * 4 + h] = s[h]; adb[(size_t)n * 4 + h] = d[h]; }
  }
}

__global__ __launch_bounds__(256) void asad1(const __half* __restrict__ xp,
                                             const float* __restrict__ as_w,
                                             const float* __restrict__ ad_w,
                                             float* __restrict__ asb, float* __restrict__ adb, int N) {
  int wave = threadIdx.x >> 6, lane = threadIdx.x & 63;
  int n = blockIdx.x * 4 + wave;
  if (n >= N) return;
  float v = __half2float(xp[(size_t)n * 64 + lane]);
  float s = wred_sum(v * as_w[lane]);
  float d = wred_sum(v * ad_w[lane]);
  if (lane == 0) { asb[n] = s; adb[n] = d; }
}

// ---------------- fused segment-softmax + aggregation, heads=4 C=64, fp16 in/out ----------------
__global__ __launch_bounds__(256) void agg_heads4(
    const __half* __restrict__ xp, const int* __restrict__ src_sorted,
    const int* __restrict__ row_start, const float* __restrict__ asb,
    const float* __restrict__ adb, const float* __restrict__ ae,
    const float* __restrict__ bias, __half* __restrict__ out, int N) {
  int wave = threadIdx.x >> 6, lane = threadIdx.x & 63;
  int n = blockIdx.x * 4 + wave;
  if (n >= N) return;
  int beg = row_start[n], end = row_start[n + 1];
  int deg = end - beg;
  int hsel = lane >> 4;
  float4 adn = *(const float4*)(adb + (size_t)n * 4);
  float4 asn = *(const float4*)(asb + (size_t)n * 4);
  float m0 = -1e30f, m1 = -1e30f, m2 = -1e30f, m3 = -1e30f;
  float aes0 = 0, aes1 = 0, aes2 = 0, aes3 = 0;
  for (int base = beg; base < end; base += 64) {
    int j = base + lane;
    if (j < end) {
      int s = src_sorted[j];
      float4 asv = *(const float4*)(asb + (size_t)s * 4);
      float4 aev = *(const float4*)(ae + (size_t)j * 4);
      aes0 += aev.x; aes1 += aev.y; aes2 += aev.z; aes3 += aev.w;
      m0 = fmaxf(m0, lrelu(asv.x + adn.x + aev.x));
      m1 = fmaxf(m1, lrelu(asv.y + adn.y + aev.y));
      m2 = fmaxf(m2, lrelu(asv.z + adn.z + aev.z));
      m3 = fmaxf(m3, lrelu(asv.w + adn.w + aev.w));
    }
  }
  m0 = wred_max(m0); m1 = wred_max(m1); m2 = wred_max(m2); m3 = wred_max(m3);
  aes0 = wred_sum(aes0); aes1 = wred_sum(aes1); aes2 = wred_sum(aes2); aes3 = wred_sum(aes3);
  float invd = 1.f / fmaxf((float)deg, 1.f);
  float al0 = lrelu(asn.x + adn.x + aes0 * invd);
  float al1 = lrelu(asn.y + adn.y + aes1 * invd);
  float al2 = lrelu(asn.z + adn.z + aes2 * invd);
  float al3 = lrelu(asn.w + adn.w + aes3 * invd);
  m0 = fmaxf(m0, al0); m1 = fmaxf(m1, al1); m2 = fmaxf(m2, al2); m3 = fmaxf(m3, al3);
  float acc0 = 0, acc1 = 0, acc2 = 0, acc3 = 0;
  float den0 = 0, den1 = 0, den2 = 0, den3 = 0;
  for (int base = beg; base < end; base += 64) {
    int j = base + lane;
    float ex0 = 0, ex1 = 0, ex2 = 0, ex3 = 0;
    int s = 0;
    if (j < end) {
      s = src_sorted[j];
      float4 asv = *(const float4*)(asb + (size_t)s * 4);
      float4 aev = *(const float4*)(ae + (size_t)j * 4);
      ex0 = __expf(lrelu(asv.x + adn.x + aev.x) - m0);
      ex1 = __expf(lrelu(asv.y + adn.y + aev.y) - m1);
      ex2 = __expf(lrelu(asv.z + adn.z + aev.z) - m2);
      ex3 = __expf(lrelu(asv.w + adn.w + aev.w) - m3);
      den0 += ex0; den1 += ex1; den2 += ex2; den3 += ex3;
    }
    int cnt = min(64, end - base);
    for (int t = 0; t < cnt; ++t) {
      int sj = __shfl(s, t);
      float w0 = __shfl(ex0, t), w1 = __shfl(ex1, t), w2 = __shfl(ex2, t), w3 = __shfl(ex3, t);
      float w = hsel == 0 ? w0 : (hsel == 1 ? w1 : (hsel == 2 ? w2 : w3));
      uint2 u = *(const uint2*)(xp + (size_t)sj * 256 + (lane << 2));
      __half2 hA = *(__half2*)&u.x;
      __half2 hB = *(__half2*)&u.y;
      float2 fA = __half22float2(hA);
      float2 fB = __half22float2(hB);
      acc0 = fmaf(w, fA.x, acc0);
      acc1 = fmaf(w, fA.y, acc1);
      acc2 = fmaf(w, fB.x, acc2);
      acc3 = fmaf(w, fB.y, acc3);
    }
  }
  den0 = wred_sum(den0); den1 = wred_sum(den1); den2 = wred_sum(den2); den3 = wred_sum(den3);
  float exl0 = __expf(al0 - m0), exl1 = __expf(al1 - m1), exl2 = __expf(al2 - m2), exl3 = __expf(al3 - m3);
  den0 += exl0; den1 += exl1; den2 += exl2; den3 += exl3;
  float exh = hsel == 0 ? exl0 : (hsel == 1 ? exl1 : (hsel == 2 ? exl2 : exl3));
  {
    uint2 u = *(const uint2*)(xp + (size_t)n * 256 + (lane << 2));
    __half2 hA = *(__half2*)&u.x;
    __half2 hB = *(__half2*)&u.y;
    float2 fA = __half22float2(hA);
    float2 fB = __half22float2(hB);
    acc0 = fmaf(exh, fA.x, acc0);
    acc1 = fmaf(exh, fA.y, acc1);
    acc2 = fmaf(exh, fB.x, acc2);
    acc3 = fmaf(exh, fB.y, acc3);
  }
  float denh = hsel == 0 ? den0 : (hsel == 1 ? den1 : (hsel == 2 ? den2 : den3));
  float rden = 1.f / (denh + 1e-16f);
  float4 bv = *(const float4*)(bias + (lane << 2));
  __half2 o01 = __floats2half2_rn(fmaxf(acc0 * rden + bv.x, 0.f), fmaxf(acc1 * rden + bv.y, 0.f));
  __half2 o23 = __floats2half2_rn(fmaxf(acc2 * rden + bv.z, 0.f), fmaxf(acc3 * rden + bv.w, 0.f));
  uint2 u;
  u.x = *(unsigned*)&o01;
  u.y = *(unsigned*)&o23;
  *(uint2*)(out + (size_t)n * 256 + (lane << 2)) = u;
}

// ---------------- layer2 (heads=1) + final linear + sigmoid, fused ----------------
__global__ __launch_bounds__(256) void agg1_final(
    const __half* __restrict__ xp, const int* __restrict__ src_sorted,
    const int* __restrict__ row_start, const float* __restrict__ asb,
    const float* __restrict__ adb, const float* __restrict__ ae,
    const float* __restrict__ b2, const float* __restrict__ lin_w,
    const float* __restrict__ lin_b, float* __restrict__ out, int N) {
  int wave = threadIdx.x >> 6, lane = threadIdx.x & 63;
  int n = blockIdx.x * 4 + wave;
  if (n >= N) return;
  int beg = row_start[n], end = row_start[n + 1];
  int deg = end - beg;
  float adn = adb[n], asn = asb[n];
  float m = -1e30f, aes = 0;
  for (int base = beg; base < end; base += 64) {
    int j = base + lane;
    if (j < end) {
      int s = src_sorted[j];
      float aev = ae[j];
      aes += aev;
      m = fmaxf(m, lrelu(asb[s] + adn + aev));
    }
  }
  m = wred_max(m);
  aes = wred_sum(aes);
  float al = lrelu(asn + adn + aes / fmaxf((float)deg, 1.f));
  m = fmaxf(m, al);
  float acc = 0, den = 0;
  for (int base = beg; base < end; base += 64) {
    int j = base + lane;
    float ex = 0;
    int s = 0;
    if (j < end) {
      s = src_sorted[j];
      ex = __expf(lrelu(asb[s] + adn + ae[j]) - m);
      den += ex;
    }
    int cnt = min(64, end - base);
    for (int t = 0; t < cnt; ++t) {
      int sj = __shfl(s, t);
      float w = __shfl(ex, t);
      acc = fmaf(w, __half2float(xp[(size_t)sj * 64 + lane]), acc);
    }
  }
  den = wred_sum(den);
  float exl = __expf(al - m);
  den += exl;
  acc = fmaf(exl, __half2float(xp[(size_t)n * 64 + lane]), acc);
  float h = fmaxf(acc / (den + 1e-16f) + b2[lane], 0.f);
  float p = wred_sum(h * lin_w[lane]);
  if (lane == 0) out[n] = 1.f / (1.f + __expf(-(p + lin_b[0])));
}

// ---------------- host glue ----------------
extern "C" void kernel_launch(void* const* d_in, const int* in_sizes, int n_in,
                              void* d_out, int out_size, void* d_ws, size_t ws_size,
                              hipStream_t stream) {
  const float* x    = (const float*)d_in[0];
  const int*   ei   = (const int*)d_in[1];
  const float* ea   = (const float*)d_in[2];
  const float* W0   = (const float*)d_in[3];
  const float* as0w = (const float*)d_in[4];
  const float* ad0w = (const float*)d_in[5];
  const float* We0  = (const float*)d_in[6];
  const float* ae0w = (const float*)d_in[7];
  const float* b0   = (const float*)d_in[8];
  const float* W1   = (const float*)d_in[9];
  const float* as1w = (const float*)d_in[10];
  const float* ad1w = (const float*)d_in[11];
  const float* We1  = (const float*)d_in[12];
  const float* ae1w = (const float*)d_in[13];
  const float* b1   = (const float*)d_in[14];
  const float* W2   = (const float*)d_in[15];
  const float* as2w = (const float*)d_in[16];
  const float* ad2w = (const float*)d_in[17];
  const float* We2  = (const float*)d_in[18];
  const float* ae2w = (const float*)d_in[19];
  const float* b2   = (const float*)d_in[20];
  const float* linw = (const float*)d_in[21];
  const float* linb = (const float*)d_in[22];

  const int N = in_sizes[0] / 128;
  const int E = in_sizes[1] / 2;
  const int* src = ei;
  const int* dst = ei + E;

  char* p = (char*)d_ws;
  auto alloc = [&](size_t bytes) {
    char* r = p;
    p += (bytes + 255) & ~size_t(255);
    return r;
  };
  __half* xh         = (__half*)alloc((size_t)N * 128 * 2);  // input converted to f16
  __half* bufAh      = (__half*)alloc((size_t)N * 256 * 2);  // agg output (f16, GEMM A)
  __half* xph        = (__half*)alloc((size_t)N * 256 * 2);  // GEMM output (f16 gather table)
  __half* W0t        = (__half*)alloc((size_t)256 * 128 * 2);
  __half* W1t        = (__half*)alloc((size_t)256 * 256 * 2);
  __half* W2t        = (__half*)alloc((size_t)64 * 256 * 2);
  float*  asb        = (float*)alloc((size_t)N * 4 * 4);
  float*  adb        = (float*)alloc((size_t)N * 4 * 4);
  int*    src_sorted = (int*)alloc((size_t)E * 4);
  int*    eid_sorted = (int*)alloc((size_t)E * 4);
  float*  ae0s       = (float*)alloc((size_t)E * 4 * 4);
  float*  ae1s       = (float*)alloc((size_t)E * 4 * 4);
  float*  ae2s       = (float*)alloc((size_t)E * 4);
  int*    deg        = (int*)alloc((size_t)N * 4);
  int*    row_start  = (int*)alloc((size_t)(N + 1) * 4);
  int*    cursor     = (int*)alloc((size_t)N * 4);
  float*  wv         = (float*)alloc(144 * 4);

  int nb = (N + 255) / 256;
  int eb = (E + 255) / 256;
  zero_int2<<<nb, 256, 0, stream>>>(deg, cursor, N);
  count_deg<<<eb, 256, 0, stream>>>(dst, deg, E);
  scan_deg<<<1, 1024, 0, stream>>>(deg, row_start, N);
  scatter_edges<<<eb, 256, 0, stream>>>(src, dst, row_start, cursor, src_sorted, eid_sorted, E);
  wvec_kernel<<<1, 160, 0, stream>>>(We0, ae0w, We1, ae1w, We2, ae2w, wv);
  edge_ae<<<eb, 256, 0, stream>>>(ea, eid_sorted, wv, ae0s, ae1s, ae2s, E);

  // weight/input conversion
  convert_f32_f16<<<(N * 128 / 4 + 255) / 256, 256, 0, stream>>>(x, xh, N * 128 / 4);
  transpose_w_f16<<<dim3(16, 8), 256, 0, stream>>>(W0, W0t, 128, 256);
  transpose_w_f16<<<dim3(16, 16), 256, 0, stream>>>(W1, W1t, 256, 256);
  transpose_w_f16<<<dim3(4, 16), 256, 0, stream>>>(W2, W2t, 256, 64);

  int gm = (N + 127) / 128;
  int nwb = (N + 3) / 4;
  // layer 0
  gemm_f16mfma<128><<<dim3(gm, 2), 256, 0, stream>>>(xh, W0t, xph, N, 128, 256);
  asad4<<<nwb, 256, 0, stream>>>(xph, as0w, ad0w, asb, adb, N);
  agg_heads4<<<nwb, 256, 0, stream>>>(xph, src_sorted, row_start, asb, adb, ae0s, b0, bufAh, N);
  // layer 1
  gemm_f16mfma<128><<<dim3(gm, 2), 256, 0, stream>>>(bufAh, W1t, xph, N, 256, 256);
  asad4<<<nwb, 256, 0, stream>>>(xph, as1w, ad1w, asb, adb, N);
  agg_heads4<<<nwb, 256, 0, stream>>>(xph, src_sorted, row_start, asb, adb, ae1s, b1, bufAh, N);
  // layer 2 + final linear + sigmoid
  gemm_f16mfma<64><<<dim3(gm, 1), 256, 0, stream>>>(bufAh, W2t, xph, N, 256, 64);
  asad1<<<nwb, 256, 0, stream>>>(xph, as2w, ad2w, asb, adb, N);
  agg1_final<<<nwb, 256, 0, stream>>>(xph, src_sorted, row_start, asb, adb, ae2s, b2, linw, linb,
                                      (float*)d_out, N);
}

// Round 4
// 492.997 us; speedup vs baseline: 1.6586x; 1.1930x over previous
//
#include <hip/hip_runtime.h>
#include <hip/hip_fp16.h>

using f16x8 = __attribute__((ext_vector_type(8))) _Float16;
using f32x4 = __attribute__((ext_vector_type(4))) float;

// ---------------- wave helpers (wave = 64 lanes on CDNA) ----------------
static __device__ __forceinline__ float wred_max(float v) {
#pragma unroll
  for (int o = 32; o > 0; o >>= 1) v = fmaxf(v, __shfl_xor(v, o));
  return v;
}
static __device__ __forceinline__ float wred_sum(float v) {
#pragma unroll
  for (int o = 32; o > 0; o >>= 1) v += __shfl_xor(v, o);
  return v;
}
static __device__ __forceinline__ float lrelu(float x) { return x > 0.f ? x : 0.2f * x; }

// ---------------- preprocessing: CSR build ----------------
__global__ void zero_int2(int* __restrict__ a, int* __restrict__ b, int n) {
  int i = blockIdx.x * blockDim.x + threadIdx.x;
  if (i < n) { a[i] = 0; b[i] = 0; }
}

__global__ void count_deg(const int* __restrict__ dst, int* __restrict__ deg, int E) {
  int i = blockIdx.x * blockDim.x + threadIdx.x;
  if (i < E) atomicAdd(&deg[dst[i]], 1);
}

// one block, 1024 threads; each thread serially scans a contiguous run, then block-scan of partials
__global__ __launch_bounds__(1024) void scan_deg(const int* __restrict__ deg,
                                                 int* __restrict__ row_start, int n) {
  __shared__ int sums[1024];
  int tid = threadIdx.x;
  int per = (n + 1023) / 1024;
  int b = tid * per, e = min(b + per, n);
  int loc = 0;
  for (int i = b; i < e; ++i) loc += deg[i];
  sums[tid] = loc;
  __syncthreads();
#pragma unroll
  for (int d = 1; d < 1024; d <<= 1) {
    int t = (tid >= d) ? sums[tid - d] : 0;
    __syncthreads();
    sums[tid] += t;
    __syncthreads();
  }
  int off = (tid ? sums[tid - 1] : 0);
  for (int i = b; i < e; ++i) { row_start[i] = off; off += deg[i]; }
  if (tid == 1023) row_start[n] = sums[1023];
}

__global__ void scatter_edges(const int* __restrict__ src, const int* __restrict__ dst,
                              const int* __restrict__ row_start, int* __restrict__ cursor,
                              int* __restrict__ src_sorted, int* __restrict__ eid_sorted, int E) {
  int i = blockIdx.x * blockDim.x + threadIdx.x;
  if (i < E) {
    int d = dst[i];
    int pos = row_start[d] + atomicAdd(&cursor[d], 1);
    src_sorted[pos] = src[i];
    eid_sorted[pos] = i;
  }
}

// ---------------- weight prep: f32 -> f16, transposed ----------------
__global__ void transpose_w_f16(const float* __restrict__ W, __half* __restrict__ Wt, int K, int Nc) {
  int n = blockIdx.x * 16 + (threadIdx.x & 15);
  int k = blockIdx.y * 16 + (threadIdx.x >> 4);
  if (n < Nc && k < K) Wt[(size_t)n * K + k] = __float2half(W[(size_t)k * Nc + n]);
}

__global__ void convert_f32_f16(const float* __restrict__ in, __half* __restrict__ out, int n4) {
  int i = blockIdx.x * blockDim.x + threadIdx.x;
  if (i < n4) {
    float4 v = *(const float4*)(in + (size_t)i * 4);
    __half2 h01 = __floats2half2_rn(v.x, v.y);
    __half2 h23 = __floats2half2_rn(v.z, v.w);
    uint2 u;
    u.x = *(unsigned*)&h01;
    u.y = *(unsigned*)&h23;
    *(uint2*)(out + (size_t)i * 4) = u;
  }
}

// ---------------- edge-coefficient vectors: wv[k][d], k=0..8 ----------------
__global__ void wvec_kernel(const float* __restrict__ We0, const float* __restrict__ ae0w,
                            const float* __restrict__ We1, const float* __restrict__ ae1w,
                            const float* __restrict__ We2, const float* __restrict__ ae2w,
                            float* __restrict__ wv) {
  int t = threadIdx.x;
  if (t < 144) {
    int k = t >> 4, d = t & 15;
    const float* We; const float* aev; int h; int HC;
    if (k < 4)      { We = We0; aev = ae0w; h = k;     HC = 256; }
    else if (k < 8) { We = We1; aev = ae1w; h = k - 4; HC = 256; }
    else            { We = We2; aev = ae2w; h = 0;     HC = 64; }
    float sum = 0.f;
#pragma unroll
    for (int c = 0; c < 64; ++c) sum += We[(size_t)d * HC + h * 64 + c] * aev[h * 64 + c];
    wv[k * 16 + d] = sum;
  }
}

__global__ __launch_bounds__(256) void edge_ae(const float* __restrict__ ea,
                                               const int* __restrict__ eid_sorted,
                                               const float* __restrict__ wv,
                                               float* __restrict__ ae0, float* __restrict__ ae1,
                                               float* __restrict__ ae2, int E) {
  __shared__ float swv[144];
  if (threadIdx.x < 144) swv[threadIdx.x] = wv[threadIdx.x];
  __syncthreads();
  int p = blockIdx.x * blockDim.x + threadIdx.x;
  if (p >= E) return;
  int e = eid_sorted[p];
  const float4* er = (const float4*)(ea + (size_t)e * 16);
  float4 v0 = er[0], v1 = er[1], v2 = er[2], v3 = er[3];
  float ev[16] = {v0.x, v0.y, v0.z, v0.w, v1.x, v1.y, v1.z, v1.w,
                  v2.x, v2.y, v2.z, v2.w, v3.x, v3.y, v3.z, v3.w};
  float r[9];
#pragma unroll
  for (int k = 0; k < 9; ++k) {
    float s = 0.f;
#pragma unroll
    for (int d = 0; d < 16; ++d) s += ev[d] * swv[k * 16 + d];
    r[k] = s;
  }
  *(float4*)(ae0 + (size_t)p * 4) = make_float4(r[0], r[1], r[2], r[3]);
  *(float4*)(ae1 + (size_t)p * 4) = make_float4(r[4], r[5], r[6], r[7]);
  ae2[p] = r[8];
}

// ---------------- f16 MFMA GEMM: C[M,Nc] = A[M,K] @ Bt[Nc,K]^T ----------------
template <int BN>
__global__ __launch_bounds__(256) void gemm_f16mfma(const __half* __restrict__ A,
                                                    const __half* __restrict__ Bt,
                                                    __half* __restrict__ C, int M, int K, int Nc) {
  constexpr int BM = 128, BK = 64;
  constexpr int LDT = BK + 8;
  constexpr int WN = BN / 2;
  constexpr int NFN = WN / 16;
  __shared__ __half As[BM][LDT];
  __shared__ __half Bs[BN][LDT];
  const int tid = threadIdx.x;
  const int lane = tid & 63, wave = tid >> 6;
  const int wr = wave >> 1, wc = wave & 1;
  const int bm = blockIdx.x * BM;
  const int bn = blockIdx.y * BN;
  const int r15 = lane & 15, kgrp = lane >> 4;
  f32x4 acc[4][NFN] = {};
  for (int k0 = 0; k0 < K; k0 += BK) {
#pragma unroll
    for (int i = 0; i < 4; ++i) {
      int chunk = tid + i * 256;
      int row = chunk >> 3, kc = (chunk & 7) * 8;
      int grow = bm + row;
      float4 v = make_float4(0, 0, 0, 0);
      if (grow < M) v = *(const float4*)(A + (size_t)grow * K + k0 + kc);
      *(float4*)&As[row][kc] = v;
    }
#pragma unroll
    for (int i = 0; i < BN / 32; ++i) {
      int chunk = tid + i * 256;
      int row = chunk >> 3, kc = (chunk & 7) * 8;
      *(float4*)&Bs[row][kc] = *(const float4*)(Bt + (size_t)(bn + row) * K + k0 + kc);
    }
    __syncthreads();
#pragma unroll
    for (int kk = 0; kk < BK; kk += 32) {
      f16x8 af[4], bf[NFN];
#pragma unroll
      for (int mi = 0; mi < 4; ++mi)
        af[mi] = *(const f16x8*)&As[wr * 64 + mi * 16 + r15][kk + kgrp * 8];
#pragma unroll
      for (int ni = 0; ni < NFN; ++ni)
        bf[ni] = *(const f16x8*)&Bs[wc * WN + ni * 16 + r15][kk + kgrp * 8];
#pragma unroll
      for (int mi = 0; mi < 4; ++mi)
#pragma unroll
        for (int ni = 0; ni < NFN; ++ni)
          acc[mi][ni] = __builtin_amdgcn_mfma_f32_16x16x32_f16(af[mi], bf[ni], acc[mi][ni], 0, 0, 0);
    }
    __syncthreads();
  }
#pragma unroll
  for (int mi = 0; mi < 4; ++mi) {
#pragma unroll
    for (int r = 0; r < 4; ++r) {
      int grow = bm + wr * 64 + mi * 16 + kgrp * 4 + r;
      if (grow < M) {
#pragma unroll
        for (int ni = 0; ni < NFN; ++ni) {
          int gcol = bn + wc * WN + ni * 16 + r15;
          C[(size_t)grow * Nc + gcol] = __float2half(acc[mi][ni][r]);
        }
      }
    }
  }
}

// ---------------- per-node a_src/a_dst dots (fp16 xp) ----------------
__global__ __launch_bounds__(256) void asad4(const __half* __restrict__ xp,
                                             const float* __restrict__ as_w,
                                             const float* __restrict__ ad_w,
                                             float* __restrict__ asb, float* __restrict__ adb, int N) {
  int wave = threadIdx.x >> 6, lane = threadIdx.x & 63;
  int n = blockIdx.x * 4 + wave;
  if (n >= N) return;
  const __half* xr = xp + (size_t)n * 256;
  float s[4], d[4];
#pragma unroll
  for (int h = 0; h < 4; ++h) {
    float v = __half2float(xr[h * 64 + lane]);
    s[h] = v * as_w[h * 64 + lane];
    d[h] = v * ad_w[h * 64 + lane];
  }
#pragma unroll
  for (int h = 0; h < 4; ++h) { s[h] = wred_sum(s[h]); d[h] = wred_sum(d[h]); }
  if (lane == 0) {
#pragma unroll
    for (int h = 0; h < 4; ++h) { asb[(size_t)n * 4 + h] = s[h]; adb[(size_t)n * 4 + h] = d[h]; }
  }
}

__global__ __launch_bounds__(256) void asad1(const __half* __restrict__ xp,
                                             const float* __restrict__ as_w,
                                             const float* __restrict__ ad_w,
                                             float* __restrict__ asb, float* __restrict__ adb, int N) {
  int wave = threadIdx.x >> 6, lane = threadIdx.x & 63;
  int n = blockIdx.x * 4 + wave;
  if (n >= N) return;
  float v = __half2float(xp[(size_t)n * 64 + lane]);
  float s = wred_sum(v * as_w[lane]);
  float d = wred_sum(v * ad_w[lane]);
  if (lane == 0) { asb[n] = s; adb[n] = d; }
}

// ---------------- fused segment-softmax + aggregation, heads=4 C=64, fp16 in/out ----------------
__global__ __launch_bounds__(256) void agg_heads4(
    const __half* __restrict__ xp, const int* __restrict__ src_sorted,
    const int* __restrict__ row_start, const float* __restrict__ asb,
    const float* __restrict__ adb, const float* __restrict__ ae,
    const float* __restrict__ bias, __half* __restrict__ out, int N) {
  __shared__ float sw[4][256];
  __shared__ int ssrc[4][64];
  int wave = threadIdx.x >> 6, lane = threadIdx.x & 63;
  int n = blockIdx.x * 4 + wave;
  if (n >= N) return;
  int beg = row_start[n], end = row_start[n + 1];
  int deg = end - beg;
  int hsel = lane >> 4;
  float4 adn = *(const float4*)(adb + (size_t)n * 4);
  float4 asn = *(const float4*)(asb + (size_t)n * 4);
  float invd = 1.f / fmaxf((float)deg, 1.f);
  float acc0 = 0, acc1 = 0, acc2 = 0, acc3 = 0;
  float den0 = 0, den1 = 0, den2 = 0, den3 = 0;
  float m0, m1, m2, m3, al0, al1, al2, al3;
  const size_t loff = (size_t)(lane << 2);

  if (deg <= 64) {
    // ---- fast path: single pass, logits in registers ----
    int j = beg + lane;
    bool act = j < end;
    int s = 0;
    float4 asv = make_float4(0, 0, 0, 0), aev = make_float4(0, 0, 0, 0);
    if (act) {
      s = src_sorted[j];
      asv = *(const float4*)(asb + (size_t)s * 4);
      aev = *(const float4*)(ae + (size_t)j * 4);
    }
    float l0 = act ? lrelu(asv.x + adn.x + aev.x) : -1e30f;
    float l1 = act ? lrelu(asv.y + adn.y + aev.y) : -1e30f;
    float l2 = act ? lrelu(asv.z + adn.z + aev.z) : -1e30f;
    float l3 = act ? lrelu(asv.w + adn.w + aev.w) : -1e30f;
    m0 = wred_max(l0); m1 = wred_max(l1); m2 = wred_max(l2); m3 = wred_max(l3);
    float aes0 = wred_sum(aev.x), aes1 = wred_sum(aev.y), aes2 = wred_sum(aev.z), aes3 = wred_sum(aev.w);
    al0 = lrelu(asn.x + adn.x + aes0 * invd);
    al1 = lrelu(asn.y + adn.y + aes1 * invd);
    al2 = lrelu(asn.z + adn.z + aes2 * invd);
    al3 = lrelu(asn.w + adn.w + aes3 * invd);
    m0 = fmaxf(m0, al0); m1 = fmaxf(m1, al1); m2 = fmaxf(m2, al2); m3 = fmaxf(m3, al3);
    float ex0 = act ? __expf(l0 - m0) : 0.f;
    float ex1 = act ? __expf(l1 - m1) : 0.f;
    float ex2 = act ? __expf(l2 - m2) : 0.f;
    float ex3 = act ? __expf(l3 - m3) : 0.f;
    den0 = wred_sum(ex0); den1 = wred_sum(ex1); den2 = wred_sum(ex2); den3 = wred_sum(ex3);
    // stage weights + src in LDS (per-wave region; DS ops in-order within wave)
    *(float4*)&sw[wave][lane << 2] = make_float4(ex0, ex1, ex2, ex3);
    ssrc[wave][lane] = s;
    asm volatile("" ::: "memory");
    int cnt = deg;
    int sj0 = ssrc[wave][0], sj1 = ssrc[wave][1], sj2 = ssrc[wave][2], sj3 = ssrc[wave][3];
    uint2 B0 = *(const uint2*)(xp + ((size_t)sj0 << 8) + loff);
    uint2 B1 = *(const uint2*)(xp + ((size_t)sj1 << 8) + loff);
    uint2 B2 = *(const uint2*)(xp + ((size_t)sj2 << 8) + loff);
    uint2 B3 = *(const uint2*)(xp + ((size_t)sj3 << 8) + loff);
    for (int t = 0; t < cnt; t += 4) {
      {
        float w = sw[wave][((t + 0) << 2) + hsel];
        float2 fA = __half22float2(*(__half2*)&B0.x);
        float2 fB = __half22float2(*(__half2*)&B0.y);
        acc0 = fmaf(w, fA.x, acc0); acc1 = fmaf(w, fA.y, acc1);
        acc2 = fmaf(w, fB.x, acc2); acc3 = fmaf(w, fB.y, acc3);
        int ns = ssrc[wave][(t + 4) & 63];
        B0 = *(const uint2*)(xp + ((size_t)ns << 8) + loff);
      }
      {
        float w = sw[wave][((t + 1) << 2) + hsel];
        float2 fA = __half22float2(*(__half2*)&B1.x);
        float2 fB = __half22float2(*(__half2*)&B1.y);
        acc0 = fmaf(w, fA.x, acc0); acc1 = fmaf(w, fA.y, acc1);
        acc2 = fmaf(w, fB.x, acc2); acc3 = fmaf(w, fB.y, acc3);
        int ns = ssrc[wave][(t + 5) & 63];
        B1 = *(const uint2*)(xp + ((size_t)ns << 8) + loff);
      }
      {
        float w = sw[wave][((t + 2) << 2) + hsel];
        float2 fA = __half22float2(*(__half2*)&B2.x);
        float2 fB = __half22float2(*(__half2*)&B2.y);
        acc0 = fmaf(w, fA.x, acc0); acc1 = fmaf(w, fA.y, acc1);
        acc2 = fmaf(w, fB.x, acc2); acc3 = fmaf(w, fB.y, acc3);
        int ns = ssrc[wave][(t + 6) & 63];
        B2 = *(const uint2*)(xp + ((size_t)ns << 8) + loff);
      }
      {
        float w = sw[wave][((t + 3) << 2) + hsel];
        float2 fA = __half22float2(*(__half2*)&B3.x);
        float2 fB = __half22float2(*(__half2*)&B3.y);
        acc0 = fmaf(w, fA.x, acc0); acc1 = fmaf(w, fA.y, acc1);
        acc2 = fmaf(w, fB.x, acc2); acc3 = fmaf(w, fB.y, acc3);
        int ns = ssrc[wave][(t + 7) & 63];
        B3 = *(const uint2*)(xp + ((size_t)ns << 8) + loff);
      }
    }
  } else {
    // ---- general path (deg > 64): original two-pass shfl-broadcast ----
    m0 = m1 = m2 = m3 = -1e30f;
    float aes0 = 0, aes1 = 0, aes2 = 0, aes3 = 0;
    for (int base = beg; base < end; base += 64) {
      int j = base + lane;
      if (j < end) {
        int s = src_sorted[j];
        float4 asv = *(const float4*)(asb + (size_t)s * 4);
        float4 aev = *(const float4*)(ae + (size_t)j * 4);
        aes0 += aev.x; aes1 += aev.y; aes2 += aev.z; aes3 += aev.w;
        m0 = fmaxf(m0, lrelu(asv.x + adn.x + aev.x));
        m1 = fmaxf(m1, lrelu(asv.y + adn.y + aev.y));
        m2 = fmaxf(m2, lrelu(asv.z + adn.z + aev.z));
        m3 = fmaxf(m3, lrelu(asv.w + adn.w + aev.w));
      }
    }
    m0 = wred_max(m0); m1 = wred_max(m1); m2 = wred_max(m2); m3 = wred_max(m3);
    aes0 = wred_sum(aes0); aes1 = wred_sum(aes1); aes2 = wred_sum(aes2); aes3 = wred_sum(aes3);
    al0 = lrelu(asn.x + adn.x + aes0 * invd);
    al1 = lrelu(asn.y + adn.y + aes1 * invd);
    al2 = lrelu(asn.z + adn.z + aes2 * invd);
    al3 = lrelu(asn.w + adn.w + aes3 * invd);
    m0 = fmaxf(m0, al0); m1 = fmaxf(m1, al1); m2 = fmaxf(m2, al2); m3 = fmaxf(m3, al3);
    for (int base = beg; base < end; base += 64) {
      int j = base + lane;
      float ex0 = 0, ex1 = 0, ex2 = 0, ex3 = 0;
      int s = 0;
      if (j < end) {
        s = src_sorted[j];
        float4 asv = *(const float4*)(asb + (size_t)s * 4);
        float4 aev = *(const float4*)(ae + (size_t)j * 4);
        ex0 = __expf(lrelu(asv.x + adn.x + aev.x) - m0);
        ex1 = __expf(lrelu(asv.y + adn.y + aev.y) - m1);
        ex2 = __expf(lrelu(asv.z + adn.z + aev.z) - m2);
        ex3 = __expf(lrelu(asv.w + adn.w + aev.w) - m3);
        den0 += ex0; den1 += ex1; den2 += ex2; den3 += ex3;
      }
      int cnt = min(64, end - base);
      for (int t = 0; t < cnt; ++t) {
        int sj = __shfl(s, t);
        float w0 = __shfl(ex0, t), w1 = __shfl(ex1, t), w2 = __shfl(ex2, t), w3 = __shfl(ex3, t);
        float w = hsel == 0 ? w0 : (hsel == 1 ? w1 : (hsel == 2 ? w2 : w3));
        uint2 u = *(const uint2*)(xp + ((size_t)sj << 8) + loff);
        float2 fA = __half22float2(*(__half2*)&u.x);
        float2 fB = __half22float2(*(__half2*)&u.y);
        acc0 = fmaf(w, fA.x, acc0);
        acc1 = fmaf(w, fA.y, acc1);
        acc2 = fmaf(w, fB.x, acc2);
        acc3 = fmaf(w, fB.y, acc3);
      }
    }
    den0 = wred_sum(den0); den1 = wred_sum(den1); den2 = wred_sum(den2); den3 = wred_sum(den3);
  }

  float exl0 = __expf(al0 - m0), exl1 = __expf(al1 - m1), exl2 = __expf(al2 - m2), exl3 = __expf(al3 - m3);
  den0 += exl0; den1 += exl1; den2 += exl2; den3 += exl3;
  float exh = hsel == 0 ? exl0 : (hsel == 1 ? exl1 : (hsel == 2 ? exl2 : exl3));
  {
    uint2 u = *(const uint2*)(xp + ((size_t)n << 8) + loff);
    float2 fA = __half22float2(*(__half2*)&u.x);
    float2 fB = __half22float2(*(__half2*)&u.y);
    acc0 = fmaf(exh, fA.x, acc0);
    acc1 = fmaf(exh, fA.y, acc1);
    acc2 = fmaf(exh, fB.x, acc2);
    acc3 = fmaf(exh, fB.y, acc3);
  }
  float denh = hsel == 0 ? den0 : (hsel == 1 ? den1 : (hsel == 2 ? den2 : den3));
  float rden = 1.f / (denh + 1e-16f);
  float4 bv = *(const float4*)(bias + (lane << 2));
  __half2 o01 = __floats2half2_rn(fmaxf(acc0 * rden + bv.x, 0.f), fmaxf(acc1 * rden + bv.y, 0.f));
  __half2 o23 = __floats2half2_rn(fmaxf(acc2 * rden + bv.z, 0.f), fmaxf(acc3 * rden + bv.w, 0.f));
  uint2 u;
  u.x = *(unsigned*)&o01;
  u.y = *(unsigned*)&o23;
  *(uint2*)(out + (size_t)n * 256 + (lane << 2)) = u;
}

// ---------------- layer2 (heads=1) + final linear + sigmoid, fused ----------------
__global__ __launch_bounds__(256) void agg1_final(
    const __half* __restrict__ xp, const int* __restrict__ src_sorted,
    const int* __restrict__ row_start, const float* __restrict__ asb,
    const float* __restrict__ adb, const float* __restrict__ ae,
    const float* __restrict__ b2, const float* __restrict__ lin_w,
    const float* __restrict__ lin_b, float* __restrict__ out, int N) {
  __shared__ float sw1[4][64];
  __shared__ int ssrc1[4][64];
  int wave = threadIdx.x >> 6, lane = threadIdx.x & 63;
  int n = blockIdx.x * 4 + wave;
  if (n >= N) return;
  int beg = row_start[n], end = row_start[n + 1];
  int deg = end - beg;
  float adn = adb[n], asn = asb[n];
  float invd = 1.f / fmaxf((float)deg, 1.f);
  float m, al, acc = 0, den = 0;

  if (deg <= 64) {
    int j = beg + lane;
    bool act = j < end;
    int s = 0;
    float aev = 0, asvs = 0;
    if (act) { s = src_sorted[j]; aev = ae[j]; asvs = asb[s]; }
    float l = act ? lrelu(asvs + adn + aev) : -1e30f;
    m = wred_max(l);
    float aes = wred_sum(aev);
    al = lrelu(asn + adn + aes * invd);
    m = fmaxf(m, al);
    float ex = act ? __expf(l - m) : 0.f;
    den = wred_sum(ex);
    sw1[wave][lane] = ex;
    ssrc1[wave][lane] = s;
    asm volatile("" ::: "memory");
    int cnt = deg;
    int sj0 = ssrc1[wave][0], sj1 = ssrc1[wave][1], sj2 = ssrc1[wave][2], sj3 = ssrc1[wave][3];
    __half H0 = xp[((size_t)sj0 << 6) + lane];
    __half H1 = xp[((size_t)sj1 << 6) + lane];
    __half H2 = xp[((size_t)sj2 << 6) + lane];
    __half H3 = xp[((size_t)sj3 << 6) + lane];
    for (int t = 0; t < cnt; t += 4) {
      {
        float w = sw1[wave][t + 0];
        acc = fmaf(w, __half2float(H0), acc);
        int ns = ssrc1[wave][(t + 4) & 63];
        H0 = xp[((size_t)ns << 6) + lane];
      }
      {
        float w = sw1[wave][t + 1];
        acc = fmaf(w, __half2float(H1), acc);
        int ns = ssrc1[wave][(t + 5) & 63];
        H1 = xp[((size_t)ns << 6) + lane];
      }
      {
        float w = sw1[wave][t + 2];
        acc = fmaf(w, __half2float(H2), acc);
        int ns = ssrc1[wave][(t + 6) & 63];
        H2 = xp[((size_t)ns << 6) + lane];
      }
      {
        float w = sw1[wave][t + 3];
        acc = fmaf(w, __half2float(H3), acc);
        int ns = ssrc1[wave][(t + 7) & 63];
        H3 = xp[((size_t)ns << 6) + lane];
      }
    }
  } else {
    m = -1e30f;
    float aes = 0;
    for (int base = beg; base < end; base += 64) {
      int j = base + lane;
      if (j < end) {
        int s = src_sorted[j];
        float aev = ae[j];
        aes += aev;
        m = fmaxf(m, lrelu(asb[s] + adn + aev));
      }
    }
    m = wred_max(m);
    aes = wred_sum(aes);
    al = lrelu(asn + adn + aes * invd);
    m = fmaxf(m, al);
    for (int base = beg; base < end; base += 64) {
      int j = base + lane;
      float ex = 0;
      int s = 0;
      if (j < end) {
        s = src_sorted[j];
        ex = __expf(lrelu(asb[s] + adn + ae[j]) - m);
        den += ex;
      }
      int cnt = min(64, end - base);
      for (int t = 0; t < cnt; ++t) {
        int sj = __shfl(s, t);
        float w = __shfl(ex, t);
        acc = fmaf(w, __half2float(xp[((size_t)sj << 6) + lane]), acc);
      }
    }
    den = wred_sum(den);
  }

  float exl = __expf(al - m);
  den += exl;
  acc = fmaf(exl, __half2float(xp[((size_t)n << 6) + lane]), acc);
  float h = fmaxf(acc / (den + 1e-16f) + b2[lane], 0.f);
  float p = wred_sum(h * lin_w[lane]);
  if (lane == 0) out[n] = 1.f / (1.f + __expf(-(p + lin_b[0])));
}

// ---------------- host glue ----------------
extern "C" void kernel_launch(void* const* d_in, const int* in_sizes, int n_in,
                              void* d_out, int out_size, void* d_ws, size_t ws_size,
                              hipStream_t stream) {
  const float* x    = (const float*)d_in[0];
  const int*   ei   = (const int*)d_in[1];
  const float* ea   = (const float*)d_in[2];
  const float* W0   = (const float*)d_in[3];
  const float* as0w = (const float*)d_in[4];
  const float* ad0w = (const float*)d_in[5];
  const float* We0  = (const float*)d_in[6];
  const float* ae0w = (const float*)d_in[7];
  const float* b0   = (const float*)d_in[8];
  const float* W1   = (const float*)d_in[9];
  const float* as1w = (const float*)d_in[10];
  const float* ad1w = (const float*)d_in[11];
  const float* We1  = (const float*)d_in[12];
  const float* ae1w = (const float*)d_in[13];
  const float* b1   = (const float*)d_in[14];
  const float* W2   = (const float*)d_in[15];
  const float* as2w = (const float*)d_in[16];
  const float* ad2w = (const float*)d_in[17];
  const float* We2  = (const float*)d_in[18];
  const float* ae2w = (const float*)d_in[19];
  const float* b2   = (const float*)d_in[20];
  const float* linw = (const float*)d_in[21];
  const float* linb = (const float*)d_in[22];

  const int N = in_sizes[0] / 128;
  const int E = in_sizes[1] / 2;
  const int* src = ei;
  const int* dst = ei + E;

  char* p = (char*)d_ws;
  auto alloc = [&](size_t bytes) {
    char* r = p;
    p += (bytes + 255) & ~size_t(255);
    return r;
  };
  __half* xh         = (__half*)alloc((size_t)N * 128 * 2);
  __half* bufAh      = (__half*)alloc((size_t)N * 256 * 2);
  __half* xph        = (__half*)alloc((size_t)N * 256 * 2);
  __half* W0t        = (__half*)alloc((size_t)256 * 128 * 2);
  __half* W1t        = (__half*)alloc((size_t)256 * 256 * 2);
  __half* W2t        = (__half*)alloc((size_t)64 * 256 * 2);
  float*  asb        = (float*)alloc((size_t)N * 4 * 4);
  float*  adb        = (float*)alloc((size_t)N * 4 * 4);
  int*    src_sorted = (int*)alloc((size_t)E * 4);
  int*    eid_sorted = (int*)alloc((size_t)E * 4);
  float*  ae0s       = (float*)alloc((size_t)E * 4 * 4);
  float*  ae1s       = (float*)alloc((size_t)E * 4 * 4);
  float*  ae2s       = (float*)alloc((size_t)E * 4);
  int*    deg        = (int*)alloc((size_t)N * 4);
  int*    row_start  = (int*)alloc((size_t)(N + 1) * 4);
  int*    cursor     = (int*)alloc((size_t)N * 4);
  float*  wv         = (float*)alloc(144 * 4);

  int nb = (N + 255) / 256;
  int eb = (E + 255) / 256;
  zero_int2<<<nb, 256, 0, stream>>>(deg, cursor, N);
  count_deg<<<eb, 256, 0, stream>>>(dst, deg, E);
  scan_deg<<<1, 1024, 0, stream>>>(deg, row_start, N);
  scatter_edges<<<eb, 256, 0, stream>>>(src, dst, row_start, cursor, src_sorted, eid_sorted, E);
  wvec_kernel<<<1, 160, 0, stream>>>(We0, ae0w, We1, ae1w, We2, ae2w, wv);
  edge_ae<<<eb, 256, 0, stream>>>(ea, eid_sorted, wv, ae0s, ae1s, ae2s, E);

  convert_f32_f16<<<(N * 128 / 4 + 255) / 256, 256, 0, stream>>>(x, xh, N * 128 / 4);
  transpose_w_f16<<<dim3(16, 8), 256, 0, stream>>>(W0, W0t, 128, 256);
  transpose_w_f16<<<dim3(16, 16), 256, 0, stream>>>(W1, W1t, 256, 256);
  transpose_w_f16<<<dim3(4, 16), 256, 0, stream>>>(W2, W2t, 256, 64);

  int gm = (N + 127) / 128;
  int nwb = (N + 3) / 4;
  // layer 0
  gemm_f16mfma<128><<<dim3(gm, 2), 256, 0, stream>>>(xh, W0t, xph, N, 128, 256);
  asad4<<<nwb, 256, 0, stream>>>(xph, as0w, ad0w, asb, adb, N);
  agg_heads4<<<nwb, 256, 0, stream>>>(xph, src_sorted, row_start, asb, adb, ae0s, b0, bufAh, N);
  // layer 1
  gemm_f16mfma<128><<<dim3(gm, 2), 256, 0, stream>>>(bufAh, W1t, xph, N, 256, 256);
  asad4<<<nwb, 256, 0, stream>>>(xph, as1w, ad1w, asb, adb, N);
  agg_heads4<<<nwb, 256, 0, stream>>>(xph, src_sorted, row_start, asb, adb, ae1s, b1, bufAh, N);
  // layer 2 + final linear + sigmoid
  gemm_f16mfma<64><<<dim3(gm, 1), 256, 0, stream>>>(bufAh, W2t, xph, N, 256, 64);
  asad1<<<nwb, 256, 0, stream>>>(xph, as2w, ad2w, asb, adb, N);
  agg1_final<<<nwb, 256, 0, stream>>>(xph, src_sorted, row_start, asb, adb, ae2s, b2, linw, linb,
                                      (float*)d_out, N);
}

// Round 5
// 423.525 us; speedup vs baseline: 1.9306x; 1.1640x over previous
//
#include <hip/hip_runtime.h>
#include <hip/hip_fp16.h>

using f16x8 = __attribute__((ext_vector_type(8))) _Float16;
using f32x4 = __attribute__((ext_vector_type(4))) float;

// ---------------- wave helpers (wave = 64 lanes on CDNA) ----------------
static __device__ __forceinline__ float wred_max(float v) {
#pragma unroll
  for (int o = 32; o > 0; o >>= 1) v = fmaxf(v, __shfl_xor(v, o));
  return v;
}
static __device__ __forceinline__ float wred_sum(float v) {
#pragma unroll
  for (int o = 32; o > 0; o >>= 1) v += __shfl_xor(v, o);
  return v;
}
static __device__ __forceinline__ float lrelu(float x) { return x > 0.f ? x : 0.2f * x; }

// ---------------- preprocessing: CSR build ----------------
__global__ void zero_int2(int* __restrict__ a, int* __restrict__ b, int n) {
  int i = blockIdx.x * blockDim.x + threadIdx.x;
  if (i < n) { a[i] = 0; b[i] = 0; }
}

__global__ void count_deg(const int* __restrict__ dst, int* __restrict__ deg, int E) {
  int i = blockIdx.x * blockDim.x + threadIdx.x;
  if (i < E) atomicAdd(&deg[dst[i]], 1);
}

// ---------------- multi-block exclusive scan (3 kernels) ----------------
__global__ __launch_bounds__(256) void scan_part(const int* __restrict__ deg,
                                                 int* __restrict__ bsum, int n) {
  __shared__ int sd[256];
  int tid = threadIdx.x;
  int i = blockIdx.x * 256 + tid;
  sd[tid] = (i < n) ? deg[i] : 0;
  __syncthreads();
#pragma unroll
  for (int d = 128; d > 0; d >>= 1) {
    if (tid < d) sd[tid] += sd[tid + d];
    __syncthreads();
  }
  if (tid == 0) bsum[blockIdx.x] = sd[0];
}

__global__ __launch_bounds__(256) void scan_bsum(const int* __restrict__ bsum,
                                                 int* __restrict__ boff, int nb) {
  __shared__ int sd[256];
  int tid = threadIdx.x;
  int v = (tid < nb) ? bsum[tid] : 0;
  sd[tid] = v;
  __syncthreads();
#pragma unroll
  for (int d = 1; d < 256; d <<= 1) {
    int t = (tid >= d) ? sd[tid - d] : 0;
    __syncthreads();
    sd[tid] += t;
    __syncthreads();
  }
  if (tid < nb) boff[tid] = sd[tid] - v;  // exclusive
}

__global__ __launch_bounds__(256) void scan_final(const int* __restrict__ deg,
                                                  const int* __restrict__ boff,
                                                  int* __restrict__ row_start, int n) {
  __shared__ int sd[256];
  int tid = threadIdx.x;
  int i = blockIdx.x * 256 + tid;
  int v = (i < n) ? deg[i] : 0;
  sd[tid] = v;
  __syncthreads();
#pragma unroll
  for (int d = 1; d < 256; d <<= 1) {
    int t = (tid >= d) ? sd[tid - d] : 0;
    __syncthreads();
    sd[tid] += t;
    __syncthreads();
  }
  int incl = sd[tid];
  int base = boff[blockIdx.x];
  if (i < n) row_start[i] = base + incl - v;
  if (i == n - 1) row_start[n] = base + incl;
}

__global__ void scatter_edges(const int* __restrict__ src, const int* __restrict__ dst,
                              const int* __restrict__ row_start, int* __restrict__ cursor,
                              int* __restrict__ src_sorted, int* __restrict__ eid_sorted, int E) {
  int i = blockIdx.x * blockDim.x + threadIdx.x;
  if (i < E) {
    int d = dst[i];
    int pos = row_start[d] + atomicAdd(&cursor[d], 1);
    src_sorted[pos] = src[i];
    eid_sorted[pos] = i;
  }
}

// ---------------- weight prep: f32 -> f16, transposed ----------------
__global__ void transpose_w_f16(const float* __restrict__ W, __half* __restrict__ Wt, int K, int Nc) {
  int n = blockIdx.x * 16 + (threadIdx.x & 15);
  int k = blockIdx.y * 16 + (threadIdx.x >> 4);
  if (n < Nc && k < K) Wt[(size_t)n * K + k] = __float2half(W[(size_t)k * Nc + n]);
}

__global__ void convert_f32_f16(const float* __restrict__ in, __half* __restrict__ out, int n4) {
  int i = blockIdx.x * blockDim.x + threadIdx.x;
  if (i < n4) {
    float4 v = *(const float4*)(in + (size_t)i * 4);
    __half2 h01 = __floats2half2_rn(v.x, v.y);
    __half2 h23 = __floats2half2_rn(v.z, v.w);
    uint2 u;
    u.x = *(unsigned*)&h01;
    u.y = *(unsigned*)&h23;
    *(uint2*)(out + (size_t)i * 4) = u;
  }
}

// ---------------- edge-coefficient vectors: wv[k][d], k=0..8 ----------------
__global__ void wvec_kernel(const float* __restrict__ We0, const float* __restrict__ ae0w,
                            const float* __restrict__ We1, const float* __restrict__ ae1w,
                            const float* __restrict__ We2, const float* __restrict__ ae2w,
                            float* __restrict__ wv) {
  int t = threadIdx.x;
  if (t < 144) {
    int k = t >> 4, d = t & 15;
    const float* We; const float* aev; int h; int HC;
    if (k < 4)      { We = We0; aev = ae0w; h = k;     HC = 256; }
    else if (k < 8) { We = We1; aev = ae1w; h = k - 4; HC = 256; }
    else            { We = We2; aev = ae2w; h = 0;     HC = 64; }
    float sum = 0.f;
#pragma unroll
    for (int c = 0; c < 64; ++c) sum += We[(size_t)d * HC + h * 64 + c] * aev[h * 64 + c];
    wv[k * 16 + d] = sum;
  }
}

__global__ __launch_bounds__(256) void edge_ae(const float* __restrict__ ea,
                                               const int* __restrict__ eid_sorted,
                                               const float* __restrict__ wv,
                                               float* __restrict__ ae0, float* __restrict__ ae1,
                                               float* __restrict__ ae2, int E) {
  __shared__ float swv[144];
  if (threadIdx.x < 144) swv[threadIdx.x] = wv[threadIdx.x];
  __syncthreads();
  int p = blockIdx.x * blockDim.x + threadIdx.x;
  if (p >= E) return;
  int e = eid_sorted[p];
  const float4* er = (const float4*)(ea + (size_t)e * 16);
  float4 v0 = er[0], v1 = er[1], v2 = er[2], v3 = er[3];
  float ev[16] = {v0.x, v0.y, v0.z, v0.w, v1.x, v1.y, v1.z, v1.w,
                  v2.x, v2.y, v2.z, v2.w, v3.x, v3.y, v3.z, v3.w};
  float r[9];
#pragma unroll
  for (int k = 0; k < 9; ++k) {
    float s = 0.f;
#pragma unroll
    for (int d = 0; d < 16; ++d) s += ev[d] * swv[k * 16 + d];
    r[k] = s;
  }
  *(float4*)(ae0 + (size_t)p * 4) = make_float4(r[0], r[1], r[2], r[3]);
  *(float4*)(ae1 + (size_t)p * 4) = make_float4(r[4], r[5], r[6], r[7]);
  ae2[p] = r[8];
}

// ---------------- f16 MFMA GEMM: C[M,Nc] = A[M,K] @ Bt[Nc,K]^T ----------------
template <int BN>
__global__ __launch_bounds__(256) void gemm_f16mfma(const __half* __restrict__ A,
                                                    const __half* __restrict__ Bt,
                                                    __half* __restrict__ C, int M, int K, int Nc) {
  constexpr int BM = 128, BK = 64;
  constexpr int LDT = BK + 8;
  constexpr int WN = BN / 2;
  constexpr int NFN = WN / 16;
  __shared__ __half As[BM][LDT];
  __shared__ __half Bs[BN][LDT];
  const int tid = threadIdx.x;
  const int lane = tid & 63, wave = tid >> 6;
  const int wr = wave >> 1, wc = wave & 1;
  const int bm = blockIdx.x * BM;
  const int bn = blockIdx.y * BN;
  const int r15 = lane & 15, kgrp = lane >> 4;
  f32x4 acc[4][NFN] = {};
  for (int k0 = 0; k0 < K; k0 += BK) {
#pragma unroll
    for (int i = 0; i < 4; ++i) {
      int chunk = tid + i * 256;
      int row = chunk >> 3, kc = (chunk & 7) * 8;
      int grow = bm + row;
      float4 v = make_float4(0, 0, 0, 0);
      if (grow < M) v = *(const float4*)(A + (size_t)grow * K + k0 + kc);
      *(float4*)&As[row][kc] = v;
    }
#pragma unroll
    for (int i = 0; i < BN / 32; ++i) {
      int chunk = tid + i * 256;
      int row = chunk >> 3, kc = (chunk & 7) * 8;
      *(float4*)&Bs[row][kc] = *(const float4*)(Bt + (size_t)(bn + row) * K + k0 + kc);
    }
    __syncthreads();
#pragma unroll
    for (int kk = 0; kk < BK; kk += 32) {
      f16x8 af[4], bf[NFN];
#pragma unroll
      for (int mi = 0; mi < 4; ++mi)
        af[mi] = *(const f16x8*)&As[wr * 64 + mi * 16 + r15][kk + kgrp * 8];
#pragma unroll
      for (int ni = 0; ni < NFN; ++ni)
        bf[ni] = *(const f16x8*)&Bs[wc * WN + ni * 16 + r15][kk + kgrp * 8];
#pragma unroll
      for (int mi = 0; mi < 4; ++mi)
#pragma unroll
        for (int ni = 0; ni < NFN; ++ni)
          acc[mi][ni] = __builtin_amdgcn_mfma_f32_16x16x32_f16(af[mi], bf[ni], acc[mi][ni], 0, 0, 0);
    }
    __syncthreads();
  }
#pragma unroll
  for (int mi = 0; mi < 4; ++mi) {
#pragma unroll
    for (int r = 0; r < 4; ++r) {
      int grow = bm + wr * 64 + mi * 16 + kgrp * 4 + r;
      if (grow < M) {
#pragma unroll
        for (int ni = 0; ni < NFN; ++ni) {
          int gcol = bn + wc * WN + ni * 16 + r15;
          C[(size_t)grow * Nc + gcol] = __float2half(acc[mi][ni][r]);
        }
      }
    }
  }
}

// ---------------- per-node a_src/a_dst dots (fp16 xp) ----------------
__global__ __launch_bounds__(256) void asad4(const __half* __restrict__ xp,
                                             const float* __restrict__ as_w,
                                             const float* __restrict__ ad_w,
                                             float* __restrict__ asb, float* __restrict__ adb, int N) {
  int wave = threadIdx.x >> 6, lane = threadIdx.x & 63;
  int n = blockIdx.x * 4 + wave;
  if (n >= N) return;
  const __half* xr = xp + (size_t)n * 256;
  float s[4], d[4];
#pragma unroll
  for (int h = 0; h < 4; ++h) {
    float v = __half2float(xr[h * 64 + lane]);
    s[h] = v * as_w[h * 64 + lane];
    d[h] = v * ad_w[h * 64 + lane];
  }
#pragma unroll
  for (int h = 0; h < 4; ++h) { s[h] = wred_sum(s[h]); d[h] = wred_sum(d[h]); }
  if (lane == 0) {
#pragma unroll
    for (int h = 0; h < 4; ++h) { asb[(size_t)n * 4 + h] = s[h]; adb[(size_t)n * 4 + h] = d[h]; }
  }
}

__global__ __launch_bounds__(256) void asad1(const __half* __restrict__ xp,
                                             const float* __restrict__ as_w,
                                             const float* __restrict__ ad_w,
                                             float* __restrict__ asb, float* __restrict__ adb, int N) {
  int wave = threadIdx.x >> 6, lane = threadIdx.x & 63;
  int n = blockIdx.x * 4 + wave;
  if (n >= N) return;
  float v = __half2float(xp[(size_t)n * 64 + lane]);
  float s = wred_sum(v * as_w[lane]);
  float d = wred_sum(v * ad_w[lane]);
  if (lane == 0) { asb[n] = s; adb[n] = d; }
}

// ---------------- fused segment-softmax + aggregation, heads=4 C=64, fp16 in/out ----------------
__global__ __launch_bounds__(256) void agg_heads4(
    const __half* __restrict__ xp, const int* __restrict__ src_sorted,
    const int* __restrict__ row_start, const float* __restrict__ asb,
    const float* __restrict__ adb, const float* __restrict__ ae,
    const float* __restrict__ bias, __half* __restrict__ out, int N) {
  __shared__ float sw[4][256];
  __shared__ int ssrc[4][64];
  int wave = threadIdx.x >> 6, lane = threadIdx.x & 63;
  int n = blockIdx.x * 4 + wave;
  if (n >= N) return;
  int beg = row_start[n], end = row_start[n + 1];
  int deg = end - beg;
  int hsel = lane >> 4;
  float4 adn = *(const float4*)(adb + (size_t)n * 4);
  float4 asn = *(const float4*)(asb + (size_t)n * 4);
  float invd = 1.f / fmaxf((float)deg, 1.f);
  float acc0 = 0, acc1 = 0, acc2 = 0, acc3 = 0;
  float den0 = 0, den1 = 0, den2 = 0, den3 = 0;
  float m0, m1, m2, m3, al0, al1, al2, al3;
  const size_t loff = (size_t)(lane << 2);

  if (deg <= 64) {
    int j = beg + lane;
    bool act = j < end;
    int s = 0;
    float4 asv = make_float4(0, 0, 0, 0), aev = make_float4(0, 0, 0, 0);
    if (act) {
      s = src_sorted[j];
      asv = *(const float4*)(asb + (size_t)s * 4);
      aev = *(const float4*)(ae + (size_t)j * 4);
    }
    float l0 = act ? lrelu(asv.x + adn.x + aev.x) : -1e30f;
    float l1 = act ? lrelu(asv.y + adn.y + aev.y) : -1e30f;
    float l2 = act ? lrelu(asv.z + adn.z + aev.z) : -1e30f;
    float l3 = act ? lrelu(asv.w + adn.w + aev.w) : -1e30f;
    m0 = wred_max(l0); m1 = wred_max(l1); m2 = wred_max(l2); m3 = wred_max(l3);
    float aes0 = wred_sum(aev.x), aes1 = wred_sum(aev.y), aes2 = wred_sum(aev.z), aes3 = wred_sum(aev.w);
    al0 = lrelu(asn.x + adn.x + aes0 * invd);
    al1 = lrelu(asn.y + adn.y + aes1 * invd);
    al2 = lrelu(asn.z + adn.z + aes2 * invd);
    al3 = lrelu(asn.w + adn.w + aes3 * invd);
    m0 = fmaxf(m0, al0); m1 = fmaxf(m1, al1); m2 = fmaxf(m2, al2); m3 = fmaxf(m3, al3);
    float ex0 = act ? __expf(l0 - m0) : 0.f;
    float ex1 = act ? __expf(l1 - m1) : 0.f;
    float ex2 = act ? __expf(l2 - m2) : 0.f;
    float ex3 = act ? __expf(l3 - m3) : 0.f;
    den0 = wred_sum(ex0); den1 = wred_sum(ex1); den2 = wred_sum(ex2); den3 = wred_sum(ex3);
    *(float4*)&sw[wave][lane << 2] = make_float4(ex0, ex1, ex2, ex3);
    ssrc[wave][lane] = s;
    asm volatile("" ::: "memory");
    int cnt = deg;
    int sj0 = ssrc[wave][0], sj1 = ssrc[wave][1], sj2 = ssrc[wave][2], sj3 = ssrc[wave][3];
    uint2 B0 = *(const uint2*)(xp + ((size_t)sj0 << 8) + loff);
    uint2 B1 = *(const uint2*)(xp + ((size_t)sj1 << 8) + loff);
    uint2 B2 = *(const uint2*)(xp + ((size_t)sj2 << 8) + loff);
    uint2 B3 = *(const uint2*)(xp + ((size_t)sj3 << 8) + loff);
    for (int t = 0; t < cnt; t += 4) {
      {
        float w = sw[wave][((t + 0) << 2) + hsel];
        float2 fA = __half22float2(*(__half2*)&B0.x);
        float2 fB = __half22float2(*(__half2*)&B0.y);
        acc0 = fmaf(w, fA.x, acc0); acc1 = fmaf(w, fA.y, acc1);
        acc2 = fmaf(w, fB.x, acc2); acc3 = fmaf(w, fB.y, acc3);
        int ns = ssrc[wave][(t + 4) & 63];
        B0 = *(const uint2*)(xp + ((size_t)ns << 8) + loff);
      }
      {
        float w = sw[wave][((t + 1) << 2) + hsel];
        float2 fA = __half22float2(*(__half2*)&B1.x);
        float2 fB = __half22float2(*(__half2*)&B1.y);
        acc0 = fmaf(w, fA.x, acc0); acc1 = fmaf(w, fA.y, acc1);
        acc2 = fmaf(w, fB.x, acc2); acc3 = fmaf(w, fB.y, acc3);
        int ns = ssrc[wave][(t + 5) & 63];
        B1 = *(const uint2*)(xp + ((size_t)ns << 8) + loff);
      }
      {
        float w = sw[wave][((t + 2) << 2) + hsel];
        float2 fA = __half22float2(*(__half2*)&B2.x);
        float2 fB = __half22float2(*(__half2*)&B2.y);
        acc0 = fmaf(w, fA.x, acc0); acc1 = fmaf(w, fA.y, acc1);
        acc2 = fmaf(w, fB.x, acc2); acc3 = fmaf(w, fB.y, acc3);
        int ns = ssrc[wave][(t + 6) & 63];
        B2 = *(const uint2*)(xp + ((size_t)ns << 8) + loff);
      }
      {
        float w = sw[wave][((t + 3) << 2) + hsel];
        float2 fA = __half22float2(*(__half2*)&B3.x);
        float2 fB = __half22float2(*(__half2*)&B3.y);
        acc0 = fmaf(w, fA.x, acc0); acc1 = fmaf(w, fA.y, acc1);
        acc2 = fmaf(w, fB.x, acc2); acc3 = fmaf(w, fB.y, acc3);
        int ns = ssrc[wave][(t + 7) & 63];
        B3 = *(const uint2*)(xp + ((size_t)ns << 8) + loff);
      }
    }
  } else {
    m0 = m1 = m2 = m3 = -1e30f;
    float aes0 = 0, aes1 = 0, aes2 = 0, aes3 = 0;
    for (int base = beg; base < end; base += 64) {
      int j = base + lane;
      if (j < end) {
        int s = src_sorted[j];
        float4 asv = *(const float4*)(asb + (size_t)s * 4);
        float4 aev = *(const float4*)(ae + (size_t)j * 4);
        aes0 += aev.x; aes1 += aev.y; aes2 += aev.z; aes3 += aev.w;
        m0 = fmaxf(m0, lrelu(asv.x + adn.x + aev.x));
        m1 = fmaxf(m1, lrelu(asv.y + adn.y + aev.y));
        m2 = fmaxf(m2, lrelu(asv.z + adn.z + aev.z));
        m3 = fmaxf(m3, lrelu(asv.w + adn.w + aev.w));
      }
    }
    m0 = wred_max(m0); m1 = wred_max(m1); m2 = wred_max(m2); m3 = wred_max(m3);
    aes0 = wred_sum(aes0); aes1 = wred_sum(aes1); aes2 = wred_sum(aes2); aes3 = wred_sum(aes3);
    al0 = lrelu(asn.x + adn.x + aes0 * invd);
    al1 = lrelu(asn.y + adn.y + aes1 * invd);
    al2 = lrelu(asn.z + adn.z + aes2 * invd);
    al3 = lrelu(asn.w + adn.w + aes3 * invd);
    m0 = fmaxf(m0, al0); m1 = fmaxf(m1, al1); m2 = fmaxf(m2, al2); m3 = fmaxf(m3, al3);
    for (int base = beg; base < end; base += 64) {
      int j = base + lane;
      float ex0 = 0, ex1 = 0, ex2 = 0, ex3 = 0;
      int s = 0;
      if (j < end) {
        s = src_sorted[j];
        float4 asv = *(const float4*)(asb + (size_t)s * 4);
        float4 aev = *(const float4*)(ae + (size_t)j * 4);
        ex0 = __expf(lrelu(asv.x + adn.x + aev.x) - m0);
        ex1 = __expf(lrelu(asv.y + adn.y + aev.y) - m1);
        ex2 = __expf(lrelu(asv.z + adn.z + aev.z) - m2);
        ex3 = __expf(lrelu(asv.w + adn.w + aev.w) - m3);
        den0 += ex0; den1 += ex1; den2 += ex2; den3 += ex3;
      }
      int cnt = min(64, end - base);
      for (int t = 0; t < cnt; ++t) {
        int sj = __shfl(s, t);
        float w0 = __shfl(ex0, t), w1 = __shfl(ex1, t), w2 = __shfl(ex2, t), w3 = __shfl(ex3, t);
        float w = hsel == 0 ? w0 : (hsel == 1 ? w1 : (hsel == 2 ? w2 : w3));
        uint2 u = *(const uint2*)(xp + ((size_t)sj << 8) + loff);
        float2 fA = __half22float2(*(__half2*)&u.x);
        float2 fB = __half22float2(*(__half2*)&u.y);
        acc0 = fmaf(w, fA.x, acc0);
        acc1 = fmaf(w, fA.y, acc1);
        acc2 = fmaf(w, fB.x, acc2);
        acc3 = fmaf(w, fB.y, acc3);
      }
    }
    den0 = wred_sum(den0); den1 = wred_sum(den1); den2 = wred_sum(den2); den3 = wred_sum(den3);
  }

  float exl0 = __expf(al0 - m0), exl1 = __expf(al1 - m1), exl2 = __expf(al2 - m2), exl3 = __expf(al3 - m3);
  den0 += exl0; den1 += exl1; den2 += exl2; den3 += exl3;
  float exh = hsel == 0 ? exl0 : (hsel == 1 ? exl1 : (hsel == 2 ? exl2 : exl3));
  {
    uint2 u = *(const uint2*)(xp + ((size_t)n << 8) + loff);
    float2 fA = __half22float2(*(__half2*)&u.x);
    float2 fB = __half22float2(*(__half2*)&u.y);
    acc0 = fmaf(exh, fA.x, acc0);
    acc1 = fmaf(exh, fA.y, acc1);
    acc2 = fmaf(exh, fB.x, acc2);
    acc3 = fmaf(exh, fB.y, acc3);
  }
  float denh = hsel == 0 ? den0 : (hsel == 1 ? den1 : (hsel == 2 ? den2 : den3));
  float rden = 1.f / (denh + 1e-16f);
  float4 bv = *(const float4*)(bias + (lane << 2));
  __half2 o01 = __floats2half2_rn(fmaxf(acc0 * rden + bv.x, 0.f), fmaxf(acc1 * rden + bv.y, 0.f));
  __half2 o23 = __floats2half2_rn(fmaxf(acc2 * rden + bv.z, 0.f), fmaxf(acc3 * rden + bv.w, 0.f));
  uint2 u;
  u.x = *(unsigned*)&o01;
  u.y = *(unsigned*)&o23;
  *(uint2*)(out + (size_t)n * 256 + (lane << 2)) = u;
}

// ---------------- layer2 (heads=1) + final linear + sigmoid, fused ----------------
__global__ __launch_bounds__(256) void agg1_final(
    const __half* __restrict__ xp, const int* __restrict__ src_sorted,
    const int* __restrict__ row_start, const float* __restrict__ asb,
    const float* __restrict__ adb, const float* __restrict__ ae,
    const float* __restrict__ b2, const float* __restrict__ lin_w,
    const float* __restrict__ lin_b, float* __restrict__ out, int N) {
  __shared__ float sw1[4][64];
  __shared__ int ssrc1[4][64];
  int wave = threadIdx.x >> 6, lane = threadIdx.x & 63;
  int n = blockIdx.x * 4 + wave;
  if (n >= N) return;
  int beg = row_start[n], end = row_start[n + 1];
  int deg = end - beg;
  float adn = adb[n], asn = asb[n];
  float invd = 1.f / fmaxf((float)deg, 1.f);
  float m, al, acc = 0, den = 0;

  if (deg <= 64) {
    int j = beg + lane;
    bool act = j < end;
    int s = 0;
    float aev = 0, asvs = 0;
    if (act) { s = src_sorted[j]; aev = ae[j]; asvs = asb[s]; }
    float l = act ? lrelu(asvs + adn + aev) : -1e30f;
    m = wred_max(l);
    float aes = wred_sum(aev);
    al = lrelu(asn + adn + aes * invd);
    m = fmaxf(m, al);
    float ex = act ? __expf(l - m) : 0.f;
    den = wred_sum(ex);
    sw1[wave][lane] = ex;
    ssrc1[wave][lane] = s;
    asm volatile("" ::: "memory");
    int cnt = deg;
    int sj0 = ssrc1[wave][0], sj1 = ssrc1[wave][1], sj2 = ssrc1[wave][2], sj3 = ssrc1[wave][3];
    __half H0 = xp[((size_t)sj0 << 6) + lane];
    __half H1 = xp[((size_t)sj1 << 6) + lane];
    __half H2 = xp[((size_t)sj2 << 6) + lane];
    __half H3 = xp[((size_t)sj3 << 6) + lane];
    for (int t = 0; t < cnt; t += 4) {
      {
        float w = sw1[wave][t + 0];
        acc = fmaf(w, __half2float(H0), acc);
        int ns = ssrc1[wave][(t + 4) & 63];
        H0 = xp[((size_t)ns << 6) + lane];
      }
      {
        float w = sw1[wave][t + 1];
        acc = fmaf(w, __half2float(H1), acc);
        int ns = ssrc1[wave][(t + 5) & 63];
        H1 = xp[((size_t)ns << 6) + lane];
      }
      {
        float w = sw1[wave][t + 2];
        acc = fmaf(w, __half2float(H2), acc);
        int ns = ssrc1[wave][(t + 6) & 63];
        H2 = xp[((size_t)ns << 6) + lane];
      }
      {
        float w = sw1[wave][t + 3];
        acc = fmaf(w, __half2float(H3), acc);
        int ns = ssrc1[wave][(t + 7) & 63];
        H3 = xp[((size_t)ns << 6) + lane];
      }
    }
  } else {
    m = -1e30f;
    float aes = 0;
    for (int base = beg; base < end; base += 64) {
      int j = base + lane;
      if (j < end) {
        int s = src_sorted[j];
        float aev = ae[j];
        aes += aev;
        m = fmaxf(m, lrelu(asb[s] + adn + aev));
      }
    }
    m = wred_max(m);
    aes = wred_sum(aes);
    al = lrelu(asn + adn + aes * invd);
    m = fmaxf(m, al);
    for (int base = beg; base < end; base += 64) {
      int j = base + lane;
      float ex = 0;
      int s = 0;
      if (j < end) {
        s = src_sorted[j];
        ex = __expf(lrelu(asb[s] + adn + ae[j]) - m);
        den += ex;
      }
      int cnt = min(64, end - base);
      for (int t = 0; t < cnt; ++t) {
        int sj = __shfl(s, t);
        float w = __shfl(ex, t);
        acc = fmaf(w, __half2float(xp[((size_t)sj << 6) + lane]), acc);
      }
    }
    den = wred_sum(den);
  }

  float exl = __expf(al - m);
  den += exl;
  acc = fmaf(exl, __half2float(xp[((size_t)n << 6) + lane]), acc);
  float h = fmaxf(acc / (den + 1e-16f) + b2[lane], 0.f);
  float p = wred_sum(h * lin_w[lane]);
  if (lane == 0) out[n] = 1.f / (1.f + __expf(-(p + lin_b[0])));
}

// ---------------- host glue ----------------
extern "C" void kernel_launch(void* const* d_in, const int* in_sizes, int n_in,
                              void* d_out, int out_size, void* d_ws, size_t ws_size,
                              hipStream_t stream) {
  const float* x    = (const float*)d_in[0];
  const int*   ei   = (const int*)d_in[1];
  const float* ea   = (const float*)d_in[2];
  const float* W0   = (const float*)d_in[3];
  const float* as0w = (const float*)d_in[4];
  const float* ad0w = (const float*)d_in[5];
  const float* We0  = (const float*)d_in[6];
  const float* ae0w = (const float*)d_in[7];
  const float* b0   = (const float*)d_in[8];
  const float* W1   = (const float*)d_in[9];
  const float* as1w = (const float*)d_in[10];
  const float* ad1w = (const float*)d_in[11];
  const float* We1  = (const float*)d_in[12];
  const float* ae1w = (const float*)d_in[13];
  const float* b1   = (const float*)d_in[14];
  const float* W2   = (const float*)d_in[15];
  const float* as2w = (const float*)d_in[16];
  const float* ad2w = (const float*)d_in[17];
  const float* We2  = (const float*)d_in[18];
  const float* ae2w = (const float*)d_in[19];
  const float* b2   = (const float*)d_in[20];
  const float* linw = (const float*)d_in[21];
  const float* linb = (const float*)d_in[22];

  const int N = in_sizes[0] / 128;
  const int E = in_sizes[1] / 2;
  const int* src = ei;
  const int* dst = ei + E;

  char* p = (char*)d_ws;
  auto alloc = [&](size_t bytes) {
    char* r = p;
    p += (bytes + 255) & ~size_t(255);
    return r;
  };
  __half* xh         = (__half*)alloc((size_t)N * 128 * 2);
  __half* bufAh      = (__half*)alloc((size_t)N * 256 * 2);
  __half* xph        = (__half*)alloc((size_t)N * 256 * 2);
  __half* W0t        = (__half*)alloc((size_t)256 * 128 * 2);
  __half* W1t        = (__half*)alloc((size_t)256 * 256 * 2);
  __half* W2t        = (__half*)alloc((size_t)64 * 256 * 2);
  float*  asb        = (float*)alloc((size_t)N * 4 * 4);
  float*  adb        = (float*)alloc((size_t)N * 4 * 4);
  int*    src_sorted = (int*)alloc((size_t)E * 4);
  int*    eid_sorted = (int*)alloc((size_t)E * 4);
  float*  ae0s       = (float*)alloc((size_t)E * 4 * 4);
  float*  ae1s       = (float*)alloc((size_t)E * 4 * 4);
  float*  ae2s       = (float*)alloc((size_t)E * 4);
  int*    deg        = (int*)alloc((size_t)N * 4);
  int*    row_start  = (int*)alloc((size_t)(N + 1) * 4);
  int*    cursor     = (int*)alloc((size_t)N * 4);
  int*    bsum       = (int*)alloc((size_t)256 * 4);
  int*    boff       = (int*)alloc((size_t)256 * 4);
  float*  wv         = (float*)alloc(144 * 4);

  int nb = (N + 255) / 256;
  int eb = (E + 255) / 256;
  zero_int2<<<nb, 256, 0, stream>>>(deg, cursor, N);
  count_deg<<<eb, 256, 0, stream>>>(dst, deg, E);
  scan_part<<<nb, 256, 0, stream>>>(deg, bsum, N);
  scan_bsum<<<1, 256, 0, stream>>>(bsum, boff, nb);
  scan_final<<<nb, 256, 0, stream>>>(deg, boff, row_start, N);
  scatter_edges<<<eb, 256, 0, stream>>>(src, dst, row_start, cursor, src_sorted, eid_sorted, E);
  wvec_kernel<<<1, 160, 0, stream>>>(We0, ae0w, We1, ae1w, We2, ae2w, wv);
  edge_ae<<<eb, 256, 0, stream>>>(ea, eid_sorted, wv, ae0s, ae1s, ae2s, E);

  convert_f32_f16<<<(N * 128 / 4 + 255) / 256, 256, 0, stream>>>(x, xh, N * 128 / 4);
  transpose_w_f16<<<dim3(16, 8), 256, 0, stream>>>(W0, W0t, 128, 256);
  transpose_w_f16<<<dim3(16, 16), 256, 0, stream>>>(W1, W1t, 256, 256);
  transpose_w_f16<<<dim3(4, 16), 256, 0, stream>>>(W2, W2t, 256, 64);

  int gm = (N + 127) / 128;
  int nwb = (N + 3) / 4;
  // layer 0
  gemm_f16mfma<128><<<dim3(gm, 2), 256, 0, stream>>>(xh, W0t, xph, N, 128, 256);
  asad4<<<nwb, 256, 0, stream>>>(xph, as0w, ad0w, asb, adb, N);
  agg_heads4<<<nwb, 256, 0, stream>>>(xph, src_sorted, row_start, asb, adb, ae0s, b0, bufAh, N);
  // layer 1
  gemm_f16mfma<128><<<dim3(gm, 2), 256, 0, stream>>>(bufAh, W1t, xph, N, 256, 256);
  asad4<<<nwb, 256, 0, stream>>>(xph, as1w, ad1w, asb, adb, N);
  agg_heads4<<<nwb, 256, 0, stream>>>(xph, src_sorted, row_start, asb, adb, ae1s, b1, bufAh, N);
  // layer 2 + final linear + sigmoid
  gemm_f16mfma<64><<<dim3(gm, 1), 256, 0, stream>>>(bufAh, W2t, xph, N, 256, 64);
  asad1<<<nwb, 256, 0, stream>>>(xph, as2w, ad2w, asb, adb, N);
  agg1_final<<<nwb, 256, 0, stream>>>(xph, src_sorted, row_start, asb, adb, ae2s, b2, linw, linb,
                                      (float*)d_out, N);
}

// Round 6
// 403.127 us; speedup vs baseline: 2.0283x; 1.0506x over previous
//
#include <hip/hip_runtime.h>
#include <hip/hip_fp16.h>

using f16x8 = __attribute__((ext_vector_type(8))) _Float16;
using f32x4 = __attribute__((ext_vector_type(4))) float;
using f32x2 = __attribute__((ext_vector_type(2))) float;

// ---------------- wave helpers (wave = 64 lanes on CDNA) ----------------
static __device__ __forceinline__ float wred_max(float v) {
#pragma unroll
  for (int o = 32; o > 0; o >>= 1) v = fmaxf(v, __shfl_xor(v, o));
  return v;
}
static __device__ __forceinline__ float wred_sum(float v) {
#pragma unroll
  for (int o = 32; o > 0; o >>= 1) v += __shfl_xor(v, o);
  return v;
}
static __device__ __forceinline__ float lrelu(float x) { return x > 0.f ? x : 0.2f * x; }

// ---------------- preprocessing: CSR build ----------------
__global__ void zero_int2(int* __restrict__ a, int* __restrict__ b, int n) {
  int i = blockIdx.x * blockDim.x + threadIdx.x;
  if (i < n) { a[i] = 0; b[i] = 0; }
}

__global__ void count_deg(const int* __restrict__ dst, int* __restrict__ deg, int E) {
  int i = blockIdx.x * blockDim.x + threadIdx.x;
  if (i < E) atomicAdd(&deg[dst[i]], 1);
}

// ---------------- multi-block exclusive scan (3 kernels) ----------------
__global__ __launch_bounds__(256) void scan_part(const int* __restrict__ deg,
                                                 int* __restrict__ bsum, int n) {
  __shared__ int sd[256];
  int tid = threadIdx.x;
  int i = blockIdx.x * 256 + tid;
  sd[tid] = (i < n) ? deg[i] : 0;
  __syncthreads();
#pragma unroll
  for (int d = 128; d > 0; d >>= 1) {
    if (tid < d) sd[tid] += sd[tid + d];
    __syncthreads();
  }
  if (tid == 0) bsum[blockIdx.x] = sd[0];
}

__global__ __launch_bounds__(256) void scan_bsum(const int* __restrict__ bsum,
                                                 int* __restrict__ boff, int nb) {
  __shared__ int sd[256];
  int tid = threadIdx.x;
  int v = (tid < nb) ? bsum[tid] : 0;
  sd[tid] = v;
  __syncthreads();
#pragma unroll
  for (int d = 1; d < 256; d <<= 1) {
    int t = (tid >= d) ? sd[tid - d] : 0;
    __syncthreads();
    sd[tid] += t;
    __syncthreads();
  }
  if (tid < nb) boff[tid] = sd[tid] - v;  // exclusive
}

__global__ __launch_bounds__(256) void scan_final(const int* __restrict__ deg,
                                                  const int* __restrict__ boff,
                                                  int* __restrict__ row_start, int n) {
  __shared__ int sd[256];
  int tid = threadIdx.x;
  int i = blockIdx.x * 256 + tid;
  int v = (i < n) ? deg[i] : 0;
  sd[tid] = v;
  __syncthreads();
#pragma unroll
  for (int d = 1; d < 256; d <<= 1) {
    int t = (tid >= d) ? sd[tid - d] : 0;
    __syncthreads();
    sd[tid] += t;
    __syncthreads();
  }
  int incl = sd[tid];
  int base = boff[blockIdx.x];
  if (i < n) row_start[i] = base + incl - v;
  if (i == n - 1) row_start[n] = base + incl;
}

// ---------------- fused scatter + per-edge attention coefficients ----------------
// reads ea coalesced in ORIGINAL edge order, writes coeffs to CSR-sorted slots
__global__ __launch_bounds__(256) void scatter_fused(
    const int* __restrict__ src, const int* __restrict__ dst, const float* __restrict__ ea,
    const int* __restrict__ row_start, int* __restrict__ cursor, const float* __restrict__ wv,
    int* __restrict__ src_sorted, float* __restrict__ ae0, float* __restrict__ ae1,
    float* __restrict__ ae2, int E) {
  __shared__ float swv[144];
  if (threadIdx.x < 144) swv[threadIdx.x] = wv[threadIdx.x];
  __syncthreads();
  int i = blockIdx.x * blockDim.x + threadIdx.x;
  if (i >= E) return;
  int d = dst[i];
  int pos = row_start[d] + atomicAdd(&cursor[d], 1);
  src_sorted[pos] = src[i];
  const float4* er = (const float4*)(ea + (size_t)i * 16);
  float4 v0 = er[0], v1 = er[1], v2 = er[2], v3 = er[3];
  float ev[16] = {v0.x, v0.y, v0.z, v0.w, v1.x, v1.y, v1.z, v1.w,
                  v2.x, v2.y, v2.z, v2.w, v3.x, v3.y, v3.z, v3.w};
  float r[9];
#pragma unroll
  for (int k = 0; k < 9; ++k) {
    float s = 0.f;
#pragma unroll
    for (int dd = 0; dd < 16; ++dd) s += ev[dd] * swv[k * 16 + dd];
    r[k] = s;
  }
  *(float4*)(ae0 + (size_t)pos * 4) = make_float4(r[0], r[1], r[2], r[3]);
  *(float4*)(ae1 + (size_t)pos * 4) = make_float4(r[4], r[5], r[6], r[7]);
  ae2[pos] = r[8];
}

// ---------------- weight prep: f32 -> f16, transposed ----------------
__global__ void transpose_w_f16(const float* __restrict__ W, __half* __restrict__ Wt, int K, int Nc) {
  int n = blockIdx.x * 16 + (threadIdx.x & 15);
  int k = blockIdx.y * 16 + (threadIdx.x >> 4);
  if (n < Nc && k < K) Wt[(size_t)n * K + k] = __float2half(W[(size_t)k * Nc + n]);
}

__global__ void convert_f32_f16(const float* __restrict__ in, __half* __restrict__ out, int n4) {
  int i = blockIdx.x * blockDim.x + threadIdx.x;
  if (i < n4) {
    float4 v = *(const float4*)(in + (size_t)i * 4);
    __half2 h01 = __floats2half2_rn(v.x, v.y);
    __half2 h23 = __floats2half2_rn(v.z, v.w);
    uint2 u;
    u.x = *(unsigned*)&h01;
    u.y = *(unsigned*)&h23;
    *(uint2*)(out + (size_t)i * 4) = u;
  }
}

// ---------------- edge-coefficient vectors: wv[k][d], k=0..8 ----------------
__global__ void wvec_kernel(const float* __restrict__ We0, const float* __restrict__ ae0w,
                            const float* __restrict__ We1, const float* __restrict__ ae1w,
                            const float* __restrict__ We2, const float* __restrict__ ae2w,
                            float* __restrict__ wv) {
  int t = threadIdx.x;
  if (t < 144) {
    int k = t >> 4, d = t & 15;
    const float* We; const float* aev; int h; int HC;
    if (k < 4)      { We = We0; aev = ae0w; h = k;     HC = 256; }
    else if (k < 8) { We = We1; aev = ae1w; h = k - 4; HC = 256; }
    else            { We = We2; aev = ae2w; h = 0;     HC = 64; }
    float sum = 0.f;
#pragma unroll
    for (int c = 0; c < 64; ++c) sum += We[(size_t)d * HC + h * 64 + c] * aev[h * 64 + c];
    wv[k * 16 + d] = sum;
  }
}

// ---------------- f16 MFMA GEMM: C[M,Nc] = A[M,K] @ Bt[Nc,K]^T ----------------
template <int BN>
__global__ __launch_bounds__(256) void gemm_f16mfma(const __half* __restrict__ A,
                                                    const __half* __restrict__ Bt,
                                                    __half* __restrict__ C, int M, int K, int Nc) {
  constexpr int BM = 128, BK = 64;
  constexpr int LDT = BK + 8;
  constexpr int WN = BN / 2;
  constexpr int NFN = WN / 16;
  __shared__ __half As[BM][LDT];
  __shared__ __half Bs[BN][LDT];
  const int tid = threadIdx.x;
  const int lane = tid & 63, wave = tid >> 6;
  const int wr = wave >> 1, wc = wave & 1;
  const int bm = blockIdx.x * BM;
  const int bn = blockIdx.y * BN;
  const int r15 = lane & 15, kgrp = lane >> 4;
  f32x4 acc[4][NFN] = {};
  for (int k0 = 0; k0 < K; k0 += BK) {
#pragma unroll
    for (int i = 0; i < 4; ++i) {
      int chunk = tid + i * 256;
      int row = chunk >> 3, kc = (chunk & 7) * 8;
      int grow = bm + row;
      float4 v = make_float4(0, 0, 0, 0);
      if (grow < M) v = *(const float4*)(A + (size_t)grow * K + k0 + kc);
      *(float4*)&As[row][kc] = v;
    }
#pragma unroll
    for (int i = 0; i < BN / 32; ++i) {
      int chunk = tid + i * 256;
      int row = chunk >> 3, kc = (chunk & 7) * 8;
      *(float4*)&Bs[row][kc] = *(const float4*)(Bt + (size_t)(bn + row) * K + k0 + kc);
    }
    __syncthreads();
#pragma unroll
    for (int kk = 0; kk < BK; kk += 32) {
      f16x8 af[4], bf[NFN];
#pragma unroll
      for (int mi = 0; mi < 4; ++mi)
        af[mi] = *(const f16x8*)&As[wr * 64 + mi * 16 + r15][kk + kgrp * 8];
#pragma unroll
      for (int ni = 0; ni < NFN; ++ni)
        bf[ni] = *(const f16x8*)&Bs[wc * WN + ni * 16 + r15][kk + kgrp * 8];
#pragma unroll
      for (int mi = 0; mi < 4; ++mi)
#pragma unroll
        for (int ni = 0; ni < NFN; ++ni)
          acc[mi][ni] = __builtin_amdgcn_mfma_f32_16x16x32_f16(af[mi], bf[ni], acc[mi][ni], 0, 0, 0);
    }
    __syncthreads();
  }
#pragma unroll
  for (int mi = 0; mi < 4; ++mi) {
#pragma unroll
    for (int r = 0; r < 4; ++r) {
      int grow = bm + wr * 64 + mi * 16 + kgrp * 4 + r;
      if (grow < M) {
#pragma unroll
        for (int ni = 0; ni < NFN; ++ni) {
          int gcol = bn + wc * WN + ni * 16 + r15;
          C[(size_t)grow * Nc + gcol] = __float2half(acc[mi][ni][r]);
        }
      }
    }
  }
}

// ---------------- per-node a_src/a_dst dots (fp16 xp) ----------------
__global__ __launch_bounds__(256) void asad4(const __half* __restrict__ xp,
                                             const float* __restrict__ as_w,
                                             const float* __restrict__ ad_w,
                                             float* __restrict__ asb, float* __restrict__ adb, int N) {
  int wave = threadIdx.x >> 6, lane = threadIdx.x & 63;
  int n = blockIdx.x * 4 + wave;
  if (n >= N) return;
  const __half* xr = xp + (size_t)n * 256;
  float s[4], d[4];
#pragma unroll
  for (int h = 0; h < 4; ++h) {
    float v = __half2float(xr[h * 64 + lane]);
    s[h] = v * as_w[h * 64 + lane];
    d[h] = v * ad_w[h * 64 + lane];
  }
#pragma unroll
  for (int h = 0; h < 4; ++h) { s[h] = wred_sum(s[h]); d[h] = wred_sum(d[h]); }
  if (lane == 0) {
#pragma unroll
    for (int h = 0; h < 4; ++h) { asb[(size_t)n * 4 + h] = s[h]; adb[(size_t)n * 4 + h] = d[h]; }
  }
}

__global__ __launch_bounds__(256) void asad1(const __half* __restrict__ xp,
                                             const float* __restrict__ as_w,
                                             const float* __restrict__ ad_w,
                                             float* __restrict__ asb, float* __restrict__ adb, int N) {
  int wave = threadIdx.x >> 6, lane = threadIdx.x & 63;
  int n = blockIdx.x * 4 + wave;
  if (n >= N) return;
  float v = __half2float(xp[(size_t)n * 64 + lane]);
  float s = wred_sum(v * as_w[lane]);
  float d = wred_sum(v * ad_w[lane]);
  if (lane == 0) { asb[n] = s; adb[n] = d; }
}

// ---------------- fused segment-softmax + aggregation, heads=4 C=64, fp16 in/out ----------------
__global__ __launch_bounds__(256) void agg_heads4(
    const __half* __restrict__ xp, const int* __restrict__ src_sorted,
    const int* __restrict__ row_start, const float* __restrict__ asb,
    const float* __restrict__ adb, const float* __restrict__ ae,
    const float* __restrict__ bias, __half* __restrict__ out, int N) {
  __shared__ float sw[4][256];
  __shared__ int ssrc[4][64];
  int wave = threadIdx.x >> 6, lane = threadIdx.x & 63;
  int n = blockIdx.x * 4 + wave;
  if (n >= N) return;
  int beg = row_start[n], end = row_start[n + 1];
  int deg = end - beg;
  int hsel = lane >> 4;
  float4 adn = *(const float4*)(adb + (size_t)n * 4);
  float4 asn = *(const float4*)(asb + (size_t)n * 4);
  float invd = 1.f / fmaxf((float)deg, 1.f);
  f32x2 acc01 = {0.f, 0.f}, acc23 = {0.f, 0.f};
  float den0 = 0, den1 = 0, den2 = 0, den3 = 0;
  float m0, m1, m2, m3, al0, al1, al2, al3;
  const size_t loff = (size_t)(lane << 2);

  if (deg <= 64) {
    int j = beg + lane;
    bool act = j < end;
    int s = 0;
    float4 asv = make_float4(0, 0, 0, 0), aev = make_float4(0, 0, 0, 0);
    if (act) {
      s = src_sorted[j];
      asv = *(const float4*)(asb + (size_t)s * 4);
      aev = *(const float4*)(ae + (size_t)j * 4);
    }
    float l0 = act ? lrelu(asv.x + adn.x + aev.x) : -1e30f;
    float l1 = act ? lrelu(asv.y + adn.y + aev.y) : -1e30f;
    float l2 = act ? lrelu(asv.z + adn.z + aev.z) : -1e30f;
    float l3 = act ? lrelu(asv.w + adn.w + aev.w) : -1e30f;
    m0 = wred_max(l0); m1 = wred_max(l1); m2 = wred_max(l2); m3 = wred_max(l3);
    float aes0 = wred_sum(aev.x), aes1 = wred_sum(aev.y), aes2 = wred_sum(aev.z), aes3 = wred_sum(aev.w);
    al0 = lrelu(asn.x + adn.x + aes0 * invd);
    al1 = lrelu(asn.y + adn.y + aes1 * invd);
    al2 = lrelu(asn.z + adn.z + aes2 * invd);
    al3 = lrelu(asn.w + adn.w + aes3 * invd);
    m0 = fmaxf(m0, al0); m1 = fmaxf(m1, al1); m2 = fmaxf(m2, al2); m3 = fmaxf(m3, al3);
    float ex0 = act ? __expf(l0 - m0) : 0.f;
    float ex1 = act ? __expf(l1 - m1) : 0.f;
    float ex2 = act ? __expf(l2 - m2) : 0.f;
    float ex3 = act ? __expf(l3 - m3) : 0.f;
    den0 = wred_sum(ex0); den1 = wred_sum(ex1); den2 = wred_sum(ex2); den3 = wred_sum(ex3);
    *(float4*)&sw[wave][lane << 2] = make_float4(ex0, ex1, ex2, ex3);
    ssrc[wave][lane] = s;
    asm volatile("" ::: "memory");
    int cnt = deg;
    // 8-deep software-pipelined gather (static indices after full unroll)
    uint2 B[8];
#pragma unroll
    for (int q = 0; q < 8; ++q) {
      int ns = ssrc[wave][q & 63];
      B[q] = *(const uint2*)(xp + ((size_t)ns << 8) + loff);
    }
    for (int t = 0; t < cnt; t += 8) {
#pragma unroll
      for (int q = 0; q < 8; ++q) {
        float w = sw[wave][((t + q) << 2) + hsel];
        float2 fA = __half22float2(*(__half2*)&B[q].x);
        float2 fB = __half22float2(*(__half2*)&B[q].y);
        f32x2 w2 = {w, w};
        acc01 = __builtin_elementwise_fma((f32x2){fA.x, fA.y}, w2, acc01);
        acc23 = __builtin_elementwise_fma((f32x2){fB.x, fB.y}, w2, acc23);
        int ns = ssrc[wave][(t + q + 8) & 63];
        B[q] = *(const uint2*)(xp + ((size_t)ns << 8) + loff);
      }
    }
  } else {
    m0 = m1 = m2 = m3 = -1e30f;
    float aes0 = 0, aes1 = 0, aes2 = 0, aes3 = 0;
    for (int base = beg; base < end; base += 64) {
      int j = base + lane;
      if (j < end) {
        int s = src_sorted[j];
        float4 asv = *(const float4*)(asb + (size_t)s * 4);
        float4 aev = *(const float4*)(ae + (size_t)j * 4);
        aes0 += aev.x; aes1 += aev.y; aes2 += aev.z; aes3 += aev.w;
        m0 = fmaxf(m0, lrelu(asv.x + adn.x + aev.x));
        m1 = fmaxf(m1, lrelu(asv.y + adn.y + aev.y));
        m2 = fmaxf(m2, lrelu(asv.z + adn.z + aev.z));
        m3 = fmaxf(m3, lrelu(asv.w + adn.w + aev.w));
      }
    }
    m0 = wred_max(m0); m1 = wred_max(m1); m2 = wred_max(m2); m3 = wred_max(m3);
    aes0 = wred_sum(aes0); aes1 = wred_sum(aes1); aes2 = wred_sum(aes2); aes3 = wred_sum(aes3);
    al0 = lrelu(asn.x + adn.x + aes0 * invd);
    al1 = lrelu(asn.y + adn.y + aes1 * invd);
    al2 = lrelu(asn.z + adn.z + aes2 * invd);
    al3 = lrelu(asn.w + adn.w + aes3 * invd);
    m0 = fmaxf(m0, al0); m1 = fmaxf(m1, al1); m2 = fmaxf(m2, al2); m3 = fmaxf(m3, al3);
    for (int base = beg; base < end; base += 64) {
      int j = base + lane;
      float ex0 = 0, ex1 = 0, ex2 = 0, ex3 = 0;
      int s = 0;
      if (j < end) {
        s = src_sorted[j];
        float4 asv = *(const float4*)(asb + (size_t)s * 4);
        float4 aev = *(const float4*)(ae + (size_t)j * 4);
        ex0 = __expf(lrelu(asv.x + adn.x + aev.x) - m0);
        ex1 = __expf(lrelu(asv.y + adn.y + aev.y) - m1);
        ex2 = __expf(lrelu(asv.z + adn.z + aev.z) - m2);
        ex3 = __expf(lrelu(asv.w + adn.w + aev.w) - m3);
        den0 += ex0; den1 += ex1; den2 += ex2; den3 += ex3;
      }
      int cnt = min(64, end - base);
      for (int t = 0; t < cnt; ++t) {
        int sj = __shfl(s, t);
        float w0 = __shfl(ex0, t), w1 = __shfl(ex1, t), w2 = __shfl(ex2, t), w3 = __shfl(ex3, t);
        float w = hsel == 0 ? w0 : (hsel == 1 ? w1 : (hsel == 2 ? w2 : w3));
        uint2 u = *(const uint2*)(xp + ((size_t)sj << 8) + loff);
        float2 fA = __half22float2(*(__half2*)&u.x);
        float2 fB = __half22float2(*(__half2*)&u.y);
        f32x2 w2v = {w, w};
        acc01 = __builtin_elementwise_fma((f32x2){fA.x, fA.y}, w2v, acc01);
        acc23 = __builtin_elementwise_fma((f32x2){fB.x, fB.y}, w2v, acc23);
      }
    }
    den0 = wred_sum(den0); den1 = wred_sum(den1); den2 = wred_sum(den2); den3 = wred_sum(den3);
  }

  float exl0 = __expf(al0 - m0), exl1 = __expf(al1 - m1), exl2 = __expf(al2 - m2), exl3 = __expf(al3 - m3);
  den0 += exl0; den1 += exl1; den2 += exl2; den3 += exl3;
  float exh = hsel == 0 ? exl0 : (hsel == 1 ? exl1 : (hsel == 2 ? exl2 : exl3));
  {
    uint2 u = *(const uint2*)(xp + ((size_t)n << 8) + loff);
    float2 fA = __half22float2(*(__half2*)&u.x);
    float2 fB = __half22float2(*(__half2*)&u.y);
    f32x2 w2v = {exh, exh};
    acc01 = __builtin_elementwise_fma((f32x2){fA.x, fA.y}, w2v, acc01);
    acc23 = __builtin_elementwise_fma((f32x2){fB.x, fB.y}, w2v, acc23);
  }
  float denh = hsel == 0 ? den0 : (hsel == 1 ? den1 : (hsel == 2 ? den2 : den3));
  float rden = 1.f / (denh + 1e-16f);
  float4 bv = *(const float4*)(bias + (lane << 2));
  __half2 o01 = __floats2half2_rn(fmaxf(acc01[0] * rden + bv.x, 0.f), fmaxf(acc01[1] * rden + bv.y, 0.f));
  __half2 o23 = __floats2half2_rn(fmaxf(acc23[0] * rden + bv.z, 0.f), fmaxf(acc23[1] * rden + bv.w, 0.f));
  uint2 u;
  u.x = *(unsigned*)&o01;
  u.y = *(unsigned*)&o23;
  *(uint2*)(out + (size_t)n * 256 + (lane << 2)) = u;
}

// ---------------- layer2 (heads=1) + final linear + sigmoid, fused ----------------
__global__ __launch_bounds__(256) void agg1_final(
    const __half* __restrict__ xp, const int* __restrict__ src_sorted,
    const int* __restrict__ row_start, const float* __restrict__ asb,
    const float* __restrict__ adb, const float* __restrict__ ae,
    const float* __restrict__ b2, const float* __restrict__ lin_w,
    const float* __restrict__ lin_b, float* __restrict__ out, int N) {
  __shared__ float sw1[4][64];
  __shared__ int ssrc1[4][64];
  int wave = threadIdx.x >> 6, lane = threadIdx.x & 63;
  int n = blockIdx.x * 4 + wave;
  if (n >= N) return;
  int beg = row_start[n], end = row_start[n + 1];
  int deg = end - beg;
  float adn = adb[n], asn = asb[n];
  float invd = 1.f / fmaxf((float)deg, 1.f);
  float m, al, acc = 0, den = 0;

  if (deg <= 64) {
    int j = beg + lane;
    bool act = j < end;
    int s = 0;
    float aev = 0, asvs = 0;
    if (act) { s = src_sorted[j]; aev = ae[j]; asvs = asb[s]; }
    float l = act ? lrelu(asvs + adn + aev) : -1e30f;
    m = wred_max(l);
    float aes = wred_sum(aev);
    al = lrelu(asn + adn + aes * invd);
    m = fmaxf(m, al);
    float ex = act ? __expf(l - m) : 0.f;
    den = wred_sum(ex);
    sw1[wave][lane] = ex;
    ssrc1[wave][lane] = s;
    asm volatile("" ::: "memory");
    int cnt = deg;
    __half H[8];
#pragma unroll
    for (int q = 0; q < 8; ++q) {
      int ns = ssrc1[wave][q & 63];
      H[q] = xp[((size_t)ns << 6) + lane];
    }
    for (int t = 0; t < cnt; t += 8) {
#pragma unroll
      for (int q = 0; q < 8; ++q) {
        float w = sw1[wave][t + q];
        acc = fmaf(w, __half2float(H[q]), acc);
        int ns = ssrc1[wave][(t + q + 8) & 63];
        H[q] = xp[((size_t)ns << 6) + lane];
      }
    }
  } else {
    m = -1e30f;
    float aes = 0;
    for (int base = beg; base < end; base += 64) {
      int j = base + lane;
      if (j < end) {
        int s = src_sorted[j];
        float aev = ae[j];
        aes += aev;
        m = fmaxf(m, lrelu(asb[s] + adn + aev));
      }
    }
    m = wred_max(m);
    aes = wred_sum(aes);
    al = lrelu(asn + adn + aes * invd);
    m = fmaxf(m, al);
    for (int base = beg; base < end; base += 64) {
      int j = base + lane;
      float ex = 0;
      int s = 0;
      if (j < end) {
        s = src_sorted[j];
        ex = __expf(lrelu(asb[s] + adn + ae[j]) - m);
        den += ex;
      }
      int cnt = min(64, end - base);
      for (int t = 0; t < cnt; ++t) {
        int sj = __shfl(s, t);
        float w = __shfl(ex, t);
        acc = fmaf(w, __half2float(xp[((size_t)sj << 6) + lane]), acc);
      }
    }
    den = wred_sum(den);
  }

  float exl = __expf(al - m);
  den += exl;
  acc = fmaf(exl, __half2float(xp[((size_t)n << 6) + lane]), acc);
  float h = fmaxf(acc / (den + 1e-16f) + b2[lane], 0.f);
  float p = wred_sum(h * lin_w[lane]);
  if (lane == 0) out[n] = 1.f / (1.f + __expf(-(p + lin_b[0])));
}

// ---------------- host glue ----------------
extern "C" void kernel_launch(void* const* d_in, const int* in_sizes, int n_in,
                              void* d_out, int out_size, void* d_ws, size_t ws_size,
                              hipStream_t stream) {
  const float* x    = (const float*)d_in[0];
  const int*   ei   = (const int*)d_in[1];
  const float* ea   = (const float*)d_in[2];
  const float* W0   = (const float*)d_in[3];
  const float* as0w = (const float*)d_in[4];
  const float* ad0w = (const float*)d_in[5];
  const float* We0  = (const float*)d_in[6];
  const float* ae0w = (const float*)d_in[7];
  const float* b0   = (const float*)d_in[8];
  const float* W1   = (const float*)d_in[9];
  const float* as1w = (const float*)d_in[10];
  const float* ad1w = (const float*)d_in[11];
  const float* We1  = (const float*)d_in[12];
  const float* ae1w = (const float*)d_in[13];
  const float* b1   = (const float*)d_in[14];
  const float* W2   = (const float*)d_in[15];
  const float* as2w = (const float*)d_in[16];
  const float* ad2w = (const float*)d_in[17];
  const float* We2  = (const float*)d_in[18];
  const float* ae2w = (const float*)d_in[19];
  const float* b2   = (const float*)d_in[20];
  const float* linw = (const float*)d_in[21];
  const float* linb = (const float*)d_in[22];

  const int N = in_sizes[0] / 128;
  const int E = in_sizes[1] / 2;
  const int* src = ei;
  const int* dst = ei + E;

  char* p = (char*)d_ws;
  auto alloc = [&](size_t bytes) {
    char* r = p;
    p += (bytes + 255) & ~size_t(255);
    return r;
  };
  __half* xh         = (__half*)alloc((size_t)N * 128 * 2);
  __half* bufAh      = (__half*)alloc((size_t)N * 256 * 2);
  __half* xph        = (__half*)alloc((size_t)N * 256 * 2);
  __half* W0t        = (__half*)alloc((size_t)256 * 128 * 2);
  __half* W1t        = (__half*)alloc((size_t)256 * 256 * 2);
  __half* W2t        = (__half*)alloc((size_t)64 * 256 * 2);
  float*  asb        = (float*)alloc((size_t)N * 4 * 4);
  float*  adb        = (float*)alloc((size_t)N * 4 * 4);
  int*    src_sorted = (int*)alloc((size_t)E * 4);
  float*  ae0s       = (float*)alloc((size_t)E * 4 * 4);
  float*  ae1s       = (float*)alloc((size_t)E * 4 * 4);
  float*  ae2s       = (float*)alloc((size_t)E * 4);
  int*    deg        = (int*)alloc((size_t)N * 4);
  int*    row_start  = (int*)alloc((size_t)(N + 1) * 4);
  int*    cursor     = (int*)alloc((size_t)N * 4);
  int*    bsum       = (int*)alloc((size_t)256 * 4);
  int*    boff       = (int*)alloc((size_t)256 * 4);
  float*  wv         = (float*)alloc(144 * 4);

  int nb = (N + 255) / 256;
  int eb = (E + 255) / 256;
  zero_int2<<<nb, 256, 0, stream>>>(deg, cursor, N);
  count_deg<<<eb, 256, 0, stream>>>(dst, deg, E);
  scan_part<<<nb, 256, 0, stream>>>(deg, bsum, N);
  scan_bsum<<<1, 256, 0, stream>>>(bsum, boff, nb);
  scan_final<<<nb, 256, 0, stream>>>(deg, boff, row_start, N);
  wvec_kernel<<<1, 160, 0, stream>>>(We0, ae0w, We1, ae1w, We2, ae2w, wv);
  scatter_fused<<<eb, 256, 0, stream>>>(src, dst, ea, row_start, cursor, wv,
                                        src_sorted, ae0s, ae1s, ae2s, E);

  convert_f32_f16<<<(N * 128 / 4 + 255) / 256, 256, 0, stream>>>(x, xh, N * 128 / 4);
  transpose_w_f16<<<dim3(16, 8), 256, 0, stream>>>(W0, W0t, 128, 256);
  transpose_w_f16<<<dim3(16, 16), 256, 0, stream>>>(W1, W1t, 256, 256);
  transpose_w_f16<<<dim3(4, 16), 256, 0, stream>>>(W2, W2t, 256, 64);

  int gm = (N + 127) / 128;
  int nwb = (N + 3) / 4;
  // layer 0
  gemm_f16mfma<128><<<dim3(gm, 2), 256, 0, stream>>>(xh, W0t, xph, N, 128, 256);
  asad4<<<nwb, 256, 0, stream>>>(xph, as0w, ad0w, asb, adb, N);
  agg_heads4<<<nwb, 256, 0, stream>>>(xph, src_sorted, row_start, asb, adb, ae0s, b0, bufAh, N);
  // layer 1
  gemm_f16mfma<128><<<dim3(gm, 2), 256, 0, stream>>>(bufAh, W1t, xph, N, 256, 256);
  asad4<<<nwb, 256, 0, stream>>>(xph, as1w, ad1w, asb, adb, N);
  agg_heads4<<<nwb, 256, 0, stream>>>(xph, src_sorted, row_start, asb, adb, ae1s, b1, bufAh, N);
  // layer 2 + final linear + sigmoid
  gemm_f16mfma<64><<<dim3(gm, 1), 256, 0, stream>>>(bufAh, W2t, xph, N, 256, 64);
  asad1<<<nwb, 256, 0, stream>>>(xph, as2w, ad2w, asb, adb, N);
  agg1_final<<<nwb, 256, 0, stream>>>(xph, src_sorted, row_start, asb, adb, ae2s, b2, linw, linb,
                                      (float*)d_out, N);
}